// Round 1
// baseline (416.370 us; speedup 1.0000x reference)
//
#include <hip/hip_runtime.h>

#define FD 20
#define DD 64

// ---------------------------------------------------------------------------
// Kernel 1: per-entity FM terms. One wave (64 lanes) per entity; lane = dim.
// Computes s_d = sum_f emb[idx_f][d], bi_d = 0.5*(s^2 - sum g^2),
// scalar = bi . h1 + sum_f w[idx_f] + extra.
// ---------------------------------------------------------------------------
__global__ __launch_bounds__(256) void entity_kernel(
    const float* __restrict__ user_emb, const float* __restrict__ item_emb,
    const float* __restrict__ w_user, const float* __restrict__ w_item,
    const float* __restrict__ bias, const float* __restrict__ h1,
    const int* __restrict__ ufeat, const int* __restrict__ ifeat,
    float* __restrict__ p_ud, float* __restrict__ su,
    float* __restrict__ q_vd, float* __restrict__ sv,
    int U, int V)
{
    int wid  = (int)((blockIdx.x * blockDim.x + threadIdx.x) >> 6);
    int lane = threadIdx.x & 63;
    if (wid >= U + V) return;

    const float* emb; const float* wv; const int* fidx; float extra;
    float* srow; float* sc;
    if (wid < U) {
        emb = user_emb; wv = w_user; fidx = ufeat + (size_t)wid * FD;
        extra = bias[0]; srow = p_ud + (size_t)wid * DD; sc = su + wid;
    } else {
        int m = wid - U;
        emb = item_emb; wv = w_item; fidx = ifeat + (size_t)m * FD;
        extra = 0.0f; srow = q_vd + (size_t)m * DD; sc = sv + m;
    }

    float s = 0.0f, ss = 0.0f, wsum = 0.0f;
#pragma unroll
    for (int f = 0; f < FD; ++f) {
        int idx = __builtin_amdgcn_readfirstlane(fidx[f]);  // wave-uniform
        float g = emb[(size_t)idx * DD + lane];             // coalesced 256B
        s += g; ss += g * g; wsum += wv[idx];
    }
    float bi   = 0.5f * (s * s - ss);
    float part = bi * h1[lane];
#pragma unroll
    for (int off = 32; off > 0; off >>= 1)
        part += __shfl_down(part, off, 64);

    srow[lane] = s;
    if (lane == 0) *sc = part + wsum + extra;
}

// ---------------------------------------------------------------------------
// Kernel 2: 64x64 Gram matrix G += M^T M over nrows rows. Each block stages a
// 64-row tile in LDS, each thread accumulates a 4x4 block of G in registers
// across its strided tiles, then one atomicAdd per entry.
// ---------------------------------------------------------------------------
typedef float float4v __attribute__((ext_vector_type(4)));

__global__ __launch_bounds__(256) void gram_kernel(
    const float* __restrict__ M, int nrows, float* __restrict__ G)
{
    __shared__ float tile[64][64];
    int t  = threadIdx.x;          // 0..255
    int i0 = (t & 15) << 2;        // 16 i-blocks
    int j0 = (t >> 4) << 2;        // 16 j-blocks
    float acc[4][4] = {};

    int ntiles = (nrows + 63) >> 6;
    for (int tt = blockIdx.x; tt < ntiles; tt += gridDim.x) {
        int row0 = tt << 6;
        __syncthreads();           // protect previous tile's compute
#pragma unroll
        for (int k = 0; k < 4; ++k) {
            int fi = t + k * 256;              // float4 index in [0,1024)
            int r  = fi >> 4;
            int c4 = (fi & 15) << 2;
            float4v v = (float4v)0.0f;
            if (row0 + r < nrows)
                v = *(const float4v*)(M + (size_t)(row0 + r) * DD + c4);
            *(float4v*)&tile[r][c4] = v;
        }
        __syncthreads();
        for (int n = 0; n < 64; ++n) {
            float4v va = *(const float4v*)&tile[n][i0];
            float4v vb = *(const float4v*)&tile[n][j0];
#pragma unroll
            for (int a = 0; a < 4; ++a)
#pragma unroll
                for (int b = 0; b < 4; ++b)
                    acc[a][b] += va[a] * vb[b];
        }
    }
#pragma unroll
    for (int a = 0; a < 4; ++a)
#pragma unroll
        for (int b = 0; b < 4; ++b)
            atomicAdd(&G[(i0 + a) * DD + (j0 + b)], acc[a][b]);
}

// ---------------------------------------------------------------------------
// Kernel 3: positive-pair term. One wave per pair.
// y = sum_d p[u][d]*q[v][d]*h2[d] + su[u] + sv[v];  contrib = 0.5 y^2 - 2 y.
// ---------------------------------------------------------------------------
__global__ __launch_bounds__(256) void pos_kernel(
    const float* __restrict__ p_ud, const float* __restrict__ su,
    const float* __restrict__ q_vd, const float* __restrict__ sv,
    const float* __restrict__ h2,
    const int* __restrict__ pu, const int* __restrict__ pi,
    int P, float* __restrict__ out)
{
    __shared__ float red[4];
    int wid  = (int)((blockIdx.x * blockDim.x + threadIdx.x) >> 6);
    int lane = threadIdx.x & 63;
    int wib  = threadIdx.x >> 6;

    float contrib = 0.0f;
    if (wid < P) {
        int u = __builtin_amdgcn_readfirstlane(pu[wid]);
        int v = __builtin_amdgcn_readfirstlane(pi[wid]);
        float d = p_ud[(size_t)u * DD + lane] * q_vd[(size_t)v * DD + lane] * h2[lane];
#pragma unroll
        for (int off = 32; off > 0; off >>= 1)
            d += __shfl_down(d, off, 64);
        if (lane == 0) {
            float y = d + su[u] + sv[v];
            contrib = 0.5f * y * y - 2.0f * y;
        }
    }
    if (lane == 0) red[wib] = contrib;
    __syncthreads();
    if (threadIdx.x == 0)
        atomicAdd(out, red[0] + red[1] + red[2] + red[3]);
}

// ---------------------------------------------------------------------------
// Kernel 4: negative term: 0.5 * sum_ij h2_i h2_j A_ij B_ij. One block.
// ---------------------------------------------------------------------------
__global__ __launch_bounds__(256) void neg_kernel(
    const float* __restrict__ A, const float* __restrict__ B,
    const float* __restrict__ h2, float* __restrict__ out)
{
    __shared__ float red[4];
    int t = threadIdx.x;
    float acc = 0.0f;
    for (int e = t; e < DD * DD; e += 256) {
        int i = e >> 6, j = e & 63;
        acc += h2[i] * h2[j] * A[e] * B[e];
    }
#pragma unroll
    for (int off = 32; off > 0; off >>= 1)
        acc += __shfl_down(acc, off, 64);
    if ((t & 63) == 0) red[t >> 6] = acc;
    __syncthreads();
    if (t == 0)
        atomicAdd(out, 0.5f * (red[0] + red[1] + red[2] + red[3]));
}

extern "C" void kernel_launch(void* const* d_in, const int* in_sizes, int n_in,
                              void* d_out, int out_size, void* d_ws, size_t ws_size,
                              hipStream_t stream)
{
    const float* user_emb = (const float*)d_in[0];
    const float* item_emb = (const float*)d_in[1];
    const float* w_user   = (const float*)d_in[2];
    const float* w_item   = (const float*)d_in[3];
    const float* bias     = (const float*)d_in[4];
    const float* h1       = (const float*)d_in[5];
    const float* h2       = (const float*)d_in[6];
    const int*   ufeat    = (const int*)d_in[7];
    const int*   ifeat    = (const int*)d_in[8];
    const int*   pu       = (const int*)d_in[9];
    const int*   pi       = (const int*)d_in[10];

    const int U = in_sizes[7] / FD;
    const int V = in_sizes[8] / FD;
    const int P = in_sizes[9];

    float* ws = (float*)d_ws;
    size_t off = 0;
    float* p_ud = ws + off; off += (size_t)U * DD;
    float* su   = ws + off; off += (size_t)U;          off = (off + 63) & ~(size_t)63;
    float* q_vd = ws + off; off += (size_t)V * DD;
    float* sv   = ws + off; off += (size_t)V;          off = (off + 63) & ~(size_t)63;
    float* A    = ws + off; off += (size_t)DD * DD;
    float* B    = ws + off; off += (size_t)DD * DD;

    float* out = (float*)d_out;

    // d_out and the Gram accumulators are poisoned before every launch.
    hipMemsetAsync(out, 0, sizeof(float) * out_size, stream);
    hipMemsetAsync(A, 0, 2 * (size_t)DD * DD * sizeof(float), stream);

    int nent = U + V;
    entity_kernel<<<(nent + 3) / 4, 256, 0, stream>>>(
        user_emb, item_emb, w_user, w_item, bias, h1,
        ufeat, ifeat, p_ud, su, q_vd, sv, U, V);

    gram_kernel<<<64, 256, 0, stream>>>(p_ud, U, A);
    gram_kernel<<<128, 256, 0, stream>>>(q_vd, V, B);

    pos_kernel<<<(P + 3) / 4, 256, 0, stream>>>(
        p_ud, su, q_vd, sv, h2, pu, pi, P, out);

    neg_kernel<<<1, 256, 0, stream>>>(A, B, h2, out);
}

// Round 2
// 252.617 us; speedup vs baseline: 1.6482x; 1.6482x over previous
//
#include <hip/hip_runtime.h>

#define FD 20
#define DD 64

typedef float float4v __attribute__((ext_vector_type(4)));

// ---------------------------------------------------------------------------
// Kernel 1: per-entity FM terms. One wave (64 lanes) per entity; lane = dim.
// s_d = sum_f emb[idx_f][d]; bi_d = 0.5*(s^2 - sum g^2);
// scalar = bi . h1 + sum_f w[idx_f] + extra.
// Indices loaded once (lanes 0..19, coalesced), distributed via shuffle ->
// readfirstlane so gather bases are SGPRs.
// ---------------------------------------------------------------------------
__global__ __launch_bounds__(256) void entity_kernel(
    const float* __restrict__ user_emb, const float* __restrict__ item_emb,
    const float* __restrict__ w_user, const float* __restrict__ w_item,
    const float* __restrict__ bias, const float* __restrict__ h1,
    const int* __restrict__ ufeat, const int* __restrict__ ifeat,
    float* __restrict__ p_ud, float* __restrict__ su,
    float* __restrict__ q_vd, float* __restrict__ sv,
    int U, int V)
{
    int wid  = (int)((blockIdx.x * blockDim.x + threadIdx.x) >> 6);
    int lane = threadIdx.x & 63;
    if (wid >= U + V) return;

    const float* emb; const float* wv; const int* fidx; float extra;
    float* srow; float* sc;
    if (wid < U) {
        emb = user_emb; wv = w_user; fidx = ufeat + (size_t)wid * FD;
        extra = bias[0]; srow = p_ud + (size_t)wid * DD; sc = su + wid;
    } else {
        int m = wid - U;
        emb = item_emb; wv = w_item; fidx = ifeat + (size_t)m * FD;
        extra = 0.0f; srow = q_vd + (size_t)m * DD; sc = sv + m;
    }

    // lanes 0..19 load the 20 feature indices + their w values
    int myidx = 0; float myw = 0.0f;
    if (lane < FD) {
        myidx = fidx[lane];
        myw   = wv[myidx];
    }

    float s = 0.0f, ss = 0.0f;
#pragma unroll
    for (int f = 0; f < FD; ++f) {
        int idx = __builtin_amdgcn_readfirstlane(__shfl(myidx, f, 64));
        float g = emb[(size_t)idx * DD + lane];   // coalesced 256B, SGPR base
        s += g; ss += g * g;
    }
    float bi   = 0.5f * (s * s - ss);
    float part = bi * h1[lane] + myw;             // myw = 0 on lanes >= 20
#pragma unroll
    for (int off = 32; off > 0; off >>= 1)
        part += __shfl_xor(part, off, 64);

    srow[lane] = s;
    if (lane == 0) *sc = part + extra;
}

// ---------------------------------------------------------------------------
// Kernel 2: 64x64 Gram partials. Each block accumulates M^T M over its strided
// 64-row tiles in registers (4x4 per thread) and stores its private 64x64
// partial to ws (NO atomics). Reduction happens in neg_reduce_kernel.
// ---------------------------------------------------------------------------
__global__ __launch_bounds__(256) void gram_kernel(
    const float* __restrict__ M, int nrows, float* __restrict__ Gpart)
{
    __shared__ float tile[64][64];
    int t  = threadIdx.x;          // 0..255
    int i0 = (t & 15) << 2;        // 16 i-blocks
    int j0 = (t >> 4) << 2;        // 16 j-blocks
    float acc[4][4] = {};

    int ntiles = (nrows + 63) >> 6;
    for (int tt = blockIdx.x; tt < ntiles; tt += gridDim.x) {
        int row0 = tt << 6;
        __syncthreads();           // protect previous tile's compute
#pragma unroll
        for (int k = 0; k < 4; ++k) {
            int fi = t + k * 256;              // float4 index in [0,1024)
            int r  = fi >> 4;
            int c4 = (fi & 15) << 2;
            float4v v = (float4v)0.0f;
            if (row0 + r < nrows)
                v = *(const float4v*)(M + (size_t)(row0 + r) * DD + c4);
            *(float4v*)&tile[r][c4] = v;
        }
        __syncthreads();
        for (int n = 0; n < 64; ++n) {
            float4v va = *(const float4v*)&tile[n][i0];
            float4v vb = *(const float4v*)&tile[n][j0];
#pragma unroll
            for (int a = 0; a < 4; ++a)
#pragma unroll
                for (int b = 0; b < 4; ++b)
                    acc[a][b] += va[a] * vb[b];
        }
    }
    float* out = Gpart + (size_t)blockIdx.x * (DD * DD);
#pragma unroll
    for (int a = 0; a < 4; ++a)
#pragma unroll
        for (int b = 0; b < 4; ++b)
            out[(i0 + a) * DD + (j0 + b)] = acc[a][b];
}

// ---------------------------------------------------------------------------
// Kernel 3: positive-pair term. 4 pairs per wave (16 lanes each, float4 rows),
// grid-stride, register accumulation, ONE atomic per block.
// ---------------------------------------------------------------------------
__global__ __launch_bounds__(256) void pos_kernel(
    const float* __restrict__ p_ud, const float* __restrict__ su,
    const float* __restrict__ q_vd, const float* __restrict__ sv,
    const float* __restrict__ h2,
    const int* __restrict__ pu, const int* __restrict__ pi,
    int P, float* __restrict__ out)
{
    __shared__ float red[4];
    int lane = threadIdx.x & 63;
    int sl   = lane & 15;              // lane within pair-group
    int sub  = lane >> 4;              // which of 4 pairs in this wave
    int wId  = blockIdx.x * 4 + (threadIdx.x >> 6);
    int nw   = gridDim.x * 4;

    float4v h2v = *(const float4v*)(h2 + sl * 4);   // loaded once

    float acc = 0.0f;
    for (int base = wId * 4; base < P; base += nw * 4) {
        int pid = base + sub;
        if (pid < P) {
            int u = pu[pid];
            int v = pi[pid];
            float4v pv = *(const float4v*)(p_ud + (size_t)u * DD + sl * 4);
            float4v qv = *(const float4v*)(q_vd + (size_t)v * DD + sl * 4);
            float d = pv.x * qv.x * h2v.x + pv.y * qv.y * h2v.y
                    + pv.z * qv.z * h2v.z + pv.w * qv.w * h2v.w;
#pragma unroll
            for (int off = 1; off < 16; off <<= 1)
                d += __shfl_xor(d, off, 64);        // reduce within 16 lanes
            if (sl == 0) {
                float y = d + su[u] + sv[v];
                acc += 0.5f * y * y - 2.0f * y;
            }
        }
    }
    // combine lanes 0,16,32,48
    acc += __shfl_xor(acc, 16, 64);
    acc += __shfl_xor(acc, 32, 64);
    if (lane == 0) red[threadIdx.x >> 6] = acc;
    __syncthreads();
    if (threadIdx.x == 0)
        atomicAdd(out, red[0] + red[1] + red[2] + red[3]);
}

// ---------------------------------------------------------------------------
// Kernel 4: reduce gram partials + negative term in one pass.
// grid = 16 blocks x 256 threads = 4096 threads, thread e owns entry e.
// loss_neg = 0.5 * sum_ij h2_i h2_j A_ij B_ij
// ---------------------------------------------------------------------------
__global__ __launch_bounds__(256) void neg_reduce_kernel(
    const float* __restrict__ PA, int nA,
    const float* __restrict__ PB, int nB,
    const float* __restrict__ h2, float* __restrict__ out)
{
    __shared__ float red[4];
    int e = blockIdx.x * 256 + threadIdx.x;   // 0..4095
    float a = 0.0f, b = 0.0f;
    for (int k = 0; k < nA; ++k) a += PA[(size_t)k * (DD * DD) + e];
    for (int k = 0; k < nB; ++k) b += PB[(size_t)k * (DD * DD) + e];
    int i = e >> 6, j = e & 63;
    float acc = h2[i] * h2[j] * a * b;
#pragma unroll
    for (int off = 32; off > 0; off >>= 1)
        acc += __shfl_xor(acc, off, 64);
    int lane = threadIdx.x & 63;
    if (lane == 0) red[threadIdx.x >> 6] = acc;
    __syncthreads();
    if (threadIdx.x == 0)
        atomicAdd(out, 0.5f * (red[0] + red[1] + red[2] + red[3]));
}

#define GRID_A 32
#define GRID_B 64

extern "C" void kernel_launch(void* const* d_in, const int* in_sizes, int n_in,
                              void* d_out, int out_size, void* d_ws, size_t ws_size,
                              hipStream_t stream)
{
    const float* user_emb = (const float*)d_in[0];
    const float* item_emb = (const float*)d_in[1];
    const float* w_user   = (const float*)d_in[2];
    const float* w_item   = (const float*)d_in[3];
    const float* bias     = (const float*)d_in[4];
    const float* h1       = (const float*)d_in[5];
    const float* h2       = (const float*)d_in[6];
    const int*   ufeat    = (const int*)d_in[7];
    const int*   ifeat    = (const int*)d_in[8];
    const int*   pu       = (const int*)d_in[9];
    const int*   pi       = (const int*)d_in[10];

    const int U = in_sizes[7] / FD;
    const int V = in_sizes[8] / FD;
    const int P = in_sizes[9];

    float* ws = (float*)d_ws;
    size_t off = 0;
    float* p_ud = ws + off; off += (size_t)U * DD;
    float* su   = ws + off; off += (size_t)U;          off = (off + 63) & ~(size_t)63;
    float* q_vd = ws + off; off += (size_t)V * DD;
    float* sv   = ws + off; off += (size_t)V;          off = (off + 63) & ~(size_t)63;
    float* PA   = ws + off; off += (size_t)GRID_A * DD * DD;
    float* PB   = ws + off; off += (size_t)GRID_B * DD * DD;

    float* out = (float*)d_out;
    hipMemsetAsync(out, 0, sizeof(float) * out_size, stream);

    int nent = U + V;
    entity_kernel<<<(nent + 3) / 4, 256, 0, stream>>>(
        user_emb, item_emb, w_user, w_item, bias, h1,
        ufeat, ifeat, p_ud, su, q_vd, sv, U, V);

    gram_kernel<<<GRID_A, 256, 0, stream>>>(p_ud, U, PA);
    gram_kernel<<<GRID_B, 256, 0, stream>>>(q_vd, V, PB);

    pos_kernel<<<512, 256, 0, stream>>>(
        p_ud, su, q_vd, sv, h2, pu, pi, P, out);

    neg_reduce_kernel<<<16, 256, 0, stream>>>(PA, GRID_A, PB, GRID_B, h2, out);
}

// Round 3
// 200.899 us; speedup vs baseline: 2.0725x; 1.2574x over previous
//
#include <hip/hip_runtime.h>

#define FD 20
#define DD 64

#define GA 64    // gram partial blocks for A (users)
#define GB 192   // gram partial blocks for B (items)

typedef float float4v __attribute__((ext_vector_type(4)));

// ---------------------------------------------------------------------------
// Kernel 1: per-entity FM terms. One wave (64 lanes) per entity; lane = dim.
// s_d = sum_f emb[idx_f][d]; bi_d = 0.5*(s^2 - sum g^2);
// scalar = bi . h1 + sum_f w[idx_f] + extra.
// ---------------------------------------------------------------------------
__global__ __launch_bounds__(256) void entity_kernel(
    const float* __restrict__ user_emb, const float* __restrict__ item_emb,
    const float* __restrict__ w_user, const float* __restrict__ w_item,
    const float* __restrict__ bias, const float* __restrict__ h1,
    const int* __restrict__ ufeat, const int* __restrict__ ifeat,
    float* __restrict__ p_ud, float* __restrict__ su,
    float* __restrict__ q_vd, float* __restrict__ sv,
    int U, int V)
{
    int wid  = (int)((blockIdx.x * blockDim.x + threadIdx.x) >> 6);
    int lane = threadIdx.x & 63;
    if (wid >= U + V) return;

    const float* emb; const float* wv; const int* fidx; float extra;
    float* srow; float* sc;
    if (wid < U) {
        emb = user_emb; wv = w_user; fidx = ufeat + (size_t)wid * FD;
        extra = bias[0]; srow = p_ud + (size_t)wid * DD; sc = su + wid;
    } else {
        int m = wid - U;
        emb = item_emb; wv = w_item; fidx = ifeat + (size_t)m * FD;
        extra = 0.0f; srow = q_vd + (size_t)m * DD; sc = sv + m;
    }

    // lanes 0..19 load the 20 feature indices + their w values
    int myidx = 0; float myw = 0.0f;
    if (lane < FD) {
        myidx = fidx[lane];
        myw   = wv[myidx];
    }

    float s = 0.0f, ss = 0.0f;
#pragma unroll
    for (int f = 0; f < FD; ++f) {
        int idx = __builtin_amdgcn_readfirstlane(__shfl(myidx, f, 64));
        float g = emb[(size_t)idx * DD + lane];   // coalesced 256B, SGPR base
        s += g; ss += g * g;
    }
    float bi   = 0.5f * (s * s - ss);
    float part = bi * h1[lane] + myw;             // myw = 0 on lanes >= 20
#pragma unroll
    for (int off = 32; off > 0; off >>= 1)
        part += __shfl_xor(part, off, 64);

    srow[lane] = s;
    if (lane == 0) *sc = part + extra;
}

// ---------------------------------------------------------------------------
// Kernel 2: fused Gram partials for A (users) and B (items) in ONE dispatch.
// Blocks [0,GA) -> A partials from p_ud; blocks [GA,GA+GB) -> B from q_vd.
// Each block: 64-row LDS tiles, 4x4 register tile per thread, plain stores.
// ---------------------------------------------------------------------------
__device__ __forceinline__ void gram_block(
    const float* __restrict__ M, int nrows, int bid, int nblk,
    float* __restrict__ Gpart)
{
    __shared__ float tile[64][64];
    int t  = threadIdx.x;          // 0..255
    int i0 = (t & 15) << 2;        // 16 i-blocks
    int j0 = (t >> 4) << 2;        // 16 j-blocks
    float acc[4][4] = {};

    int ntiles = (nrows + 63) >> 6;
    for (int tt = bid; tt < ntiles; tt += nblk) {
        int row0 = tt << 6;
        __syncthreads();           // protect previous tile's compute
#pragma unroll
        for (int k = 0; k < 4; ++k) {
            int fi = t + k * 256;              // float4 index in [0,1024)
            int r  = fi >> 4;
            int c4 = (fi & 15) << 2;
            float4v v = (float4v)0.0f;
            if (row0 + r < nrows)
                v = *(const float4v*)(M + (size_t)(row0 + r) * DD + c4);
            *(float4v*)&tile[r][c4] = v;
        }
        __syncthreads();
        for (int n = 0; n < 64; ++n) {
            float4v va = *(const float4v*)&tile[n][i0];
            float4v vb = *(const float4v*)&tile[n][j0];
#pragma unroll
            for (int a = 0; a < 4; ++a)
#pragma unroll
                for (int b = 0; b < 4; ++b)
                    acc[a][b] += va[a] * vb[b];
        }
    }
    float* out = Gpart + (size_t)bid * (DD * DD);
#pragma unroll
    for (int a = 0; a < 4; ++a)
#pragma unroll
        for (int b = 0; b < 4; ++b)
            out[(i0 + a) * DD + (j0 + b)] = acc[a][b];
}

__global__ __launch_bounds__(256) void gram_ab_kernel(
    const float* __restrict__ P, int U, float* __restrict__ PA,
    const float* __restrict__ Q, int V, float* __restrict__ PB)
{
    if (blockIdx.x < GA)
        gram_block(P, U, blockIdx.x, GA, PA);
    else
        gram_block(Q, V, blockIdx.x - GA, GB, PB);
}

// ---------------------------------------------------------------------------
// Kernel 3: positive-pair term. 4 pairs per wave (16 lanes each, float4 rows),
// grid-stride, register accumulation, ONE atomic per block.
// ---------------------------------------------------------------------------
__global__ __launch_bounds__(256) void pos_kernel(
    const float* __restrict__ p_ud, const float* __restrict__ su,
    const float* __restrict__ q_vd, const float* __restrict__ sv,
    const float* __restrict__ h2,
    const int* __restrict__ pu, const int* __restrict__ pi,
    int P, float* __restrict__ out)
{
    __shared__ float red[4];
    int lane = threadIdx.x & 63;
    int sl   = lane & 15;              // lane within pair-group
    int sub  = lane >> 4;              // which of 4 pairs in this wave
    int wId  = blockIdx.x * 4 + (threadIdx.x >> 6);
    int nw   = gridDim.x * 4;

    float4v h2v = *(const float4v*)(h2 + sl * 4);   // loaded once

    float acc = 0.0f;
    for (int base = wId * 4; base < P; base += nw * 4) {
        int pid = base + sub;
        if (pid < P) {
            int u = pu[pid];
            int v = pi[pid];
            float4v pv = *(const float4v*)(p_ud + (size_t)u * DD + sl * 4);
            float4v qv = *(const float4v*)(q_vd + (size_t)v * DD + sl * 4);
            float d = pv.x * qv.x * h2v.x + pv.y * qv.y * h2v.y
                    + pv.z * qv.z * h2v.z + pv.w * qv.w * h2v.w;
#pragma unroll
            for (int off = 1; off < 16; off <<= 1)
                d += __shfl_xor(d, off, 64);        // reduce within 16 lanes
            if (sl == 0) {
                float y = d + su[u] + sv[v];
                acc += 0.5f * y * y - 2.0f * y;
            }
        }
    }
    // combine lanes 0,16,32,48
    acc += __shfl_xor(acc, 16, 64);
    acc += __shfl_xor(acc, 32, 64);
    if (lane == 0) red[threadIdx.x >> 6] = acc;
    __syncthreads();
    if (threadIdx.x == 0)
        atomicAdd(out, red[0] + red[1] + red[2] + red[3]);
}

// ---------------------------------------------------------------------------
// Kernel 4: reduce gram partials + negative term in one pass.
// grid = 16 blocks x 256 threads = 4096 threads, thread e owns entry e.
// loss_neg = 0.5 * sum_ij h2_i h2_j A_ij B_ij
// ---------------------------------------------------------------------------
__global__ __launch_bounds__(256) void neg_reduce_kernel(
    const float* __restrict__ PA, const float* __restrict__ PB,
    const float* __restrict__ h2, float* __restrict__ out)
{
    __shared__ float red[4];
    int e = blockIdx.x * 256 + threadIdx.x;   // 0..4095
    float a = 0.0f, b = 0.0f;
    for (int k = 0; k < GA; ++k) a += PA[(size_t)k * (DD * DD) + e];
    for (int k = 0; k < GB; ++k) b += PB[(size_t)k * (DD * DD) + e];
    int i = e >> 6, j = e & 63;
    float acc = h2[i] * h2[j] * a * b;
#pragma unroll
    for (int off = 32; off > 0; off >>= 1)
        acc += __shfl_xor(acc, off, 64);
    int lane = threadIdx.x & 63;
    if (lane == 0) red[threadIdx.x >> 6] = acc;
    __syncthreads();
    if (threadIdx.x == 0)
        atomicAdd(out, 0.5f * (red[0] + red[1] + red[2] + red[3]));
}

extern "C" void kernel_launch(void* const* d_in, const int* in_sizes, int n_in,
                              void* d_out, int out_size, void* d_ws, size_t ws_size,
                              hipStream_t stream)
{
    const float* user_emb = (const float*)d_in[0];
    const float* item_emb = (const float*)d_in[1];
    const float* w_user   = (const float*)d_in[2];
    const float* w_item   = (const float*)d_in[3];
    const float* bias     = (const float*)d_in[4];
    const float* h1       = (const float*)d_in[5];
    const float* h2       = (const float*)d_in[6];
    const int*   ufeat    = (const int*)d_in[7];
    const int*   ifeat    = (const int*)d_in[8];
    const int*   pu       = (const int*)d_in[9];
    const int*   pi       = (const int*)d_in[10];

    const int U = in_sizes[7] / FD;
    const int V = in_sizes[8] / FD;
    const int P = in_sizes[9];

    float* ws = (float*)d_ws;
    size_t off = 0;
    float* p_ud = ws + off; off += (size_t)U * DD;
    float* su   = ws + off; off += (size_t)U;          off = (off + 63) & ~(size_t)63;
    float* q_vd = ws + off; off += (size_t)V * DD;
    float* sv   = ws + off; off += (size_t)V;          off = (off + 63) & ~(size_t)63;
    float* PA   = ws + off; off += (size_t)GA * DD * DD;
    float* PB   = ws + off; off += (size_t)GB * DD * DD;

    float* out = (float*)d_out;
    hipMemsetAsync(out, 0, sizeof(float) * out_size, stream);

    int nent = U + V;
    entity_kernel<<<(nent + 3) / 4, 256, 0, stream>>>(
        user_emb, item_emb, w_user, w_item, bias, h1,
        ufeat, ifeat, p_ud, su, q_vd, sv, U, V);

    gram_ab_kernel<<<GA + GB, 256, 0, stream>>>(p_ud, U, PA, q_vd, V, PB);

    pos_kernel<<<2048, 256, 0, stream>>>(
        p_ud, su, q_vd, sv, h2, pu, pi, P, out);

    neg_reduce_kernel<<<16, 256, 0, stream>>>(PA, PB, h2, out);
}

// Round 4
// 195.234 us; speedup vs baseline: 2.1327x; 1.0290x over previous
//
#include <hip/hip_runtime.h>

#define FD 20
#define DD 64

#define GA 64     // gram partial blocks for A (users)
#define GB 192    // gram partial blocks for B (items)
#define POSB 2048 // pos blocks in fused mid kernel

typedef float float4v __attribute__((ext_vector_type(4)));

// ---------------------------------------------------------------------------
// Kernel 1: per-entity FM terms. One wave per entity; lane = dim.
// Restructured for ILP: all 20 gathers issued before any accumulation.
// ---------------------------------------------------------------------------
__global__ __launch_bounds__(256) void entity_kernel(
    const float* __restrict__ user_emb, const float* __restrict__ item_emb,
    const float* __restrict__ w_user, const float* __restrict__ w_item,
    const float* __restrict__ bias, const float* __restrict__ h1,
    const int* __restrict__ ufeat, const int* __restrict__ ifeat,
    float* __restrict__ p_ud, float* __restrict__ su,
    float* __restrict__ q_vd, float* __restrict__ sv,
    int U, int V)
{
    int wid  = (int)((blockIdx.x * blockDim.x + threadIdx.x) >> 6);
    int lane = threadIdx.x & 63;
    if (wid >= U + V) return;

    const float* emb; const float* wv; const int* fidx; float extra;
    float* srow; float* sc;
    if (wid < U) {
        emb = user_emb; wv = w_user; fidx = ufeat + (size_t)wid * FD;
        extra = bias[0]; srow = p_ud + (size_t)wid * DD; sc = su + wid;
    } else {
        int m = wid - U;
        emb = item_emb; wv = w_item; fidx = ifeat + (size_t)m * FD;
        extra = 0.0f; srow = q_vd + (size_t)m * DD; sc = sv + m;
    }

    // lanes 0..19 load the 20 feature indices + their w values
    int myidx = 0; float myw = 0.0f;
    if (lane < FD) {
        myidx = fidx[lane];
        myw   = wv[myidx];
    }

    // distribute indices to SGPRs
    int idx[FD];
#pragma unroll
    for (int f = 0; f < FD; ++f)
        idx[f] = __builtin_amdgcn_readfirstlane(__shfl(myidx, f, 64));

    // issue ALL 20 gathers back-to-back (no accumulation dependency)
    float g[FD];
#pragma unroll
    for (int f = 0; f < FD; ++f)
        g[f] = emb[(size_t)idx[f] * DD + lane];

    float s = 0.0f, ss = 0.0f;
#pragma unroll
    for (int f = 0; f < FD; ++f) {
        s += g[f]; ss += g[f] * g[f];
    }

    float bi   = 0.5f * (s * s - ss);
    float part = bi * h1[lane] + myw;             // myw = 0 on lanes >= 20
#pragma unroll
    for (int off = 32; off > 0; off >>= 1)
        part += __shfl_xor(part, off, 64);

    srow[lane] = s;
    if (lane == 0) *sc = part + extra;
}

// ---------------------------------------------------------------------------
// Gram partial block: 64-row LDS tiles, 4x4 register tile/thread, plain store.
// ---------------------------------------------------------------------------
__device__ __forceinline__ void gram_block(
    const float* __restrict__ M, int nrows, int bid, int nblk,
    float* __restrict__ Gpart)
{
    __shared__ float tile[64][64];
    int t  = threadIdx.x;          // 0..255
    int i0 = (t & 15) << 2;
    int j0 = (t >> 4) << 2;
    float acc[4][4] = {};

    int ntiles = (nrows + 63) >> 6;
    for (int tt = bid; tt < ntiles; tt += nblk) {
        int row0 = tt << 6;
        __syncthreads();
#pragma unroll
        for (int k = 0; k < 4; ++k) {
            int fi = t + k * 256;
            int r  = fi >> 4;
            int c4 = (fi & 15) << 2;
            float4v v = (float4v)0.0f;
            if (row0 + r < nrows)
                v = *(const float4v*)(M + (size_t)(row0 + r) * DD + c4);
            *(float4v*)&tile[r][c4] = v;
        }
        __syncthreads();
        for (int n = 0; n < 64; ++n) {
            float4v va = *(const float4v*)&tile[n][i0];
            float4v vb = *(const float4v*)&tile[n][j0];
#pragma unroll
            for (int a = 0; a < 4; ++a)
#pragma unroll
                for (int b = 0; b < 4; ++b)
                    acc[a][b] += va[a] * vb[b];
        }
    }
    float* out = Gpart + (size_t)bid * (DD * DD);
#pragma unroll
    for (int a = 0; a < 4; ++a)
#pragma unroll
        for (int b = 0; b < 4; ++b)
            out[(i0 + a) * DD + (j0 + b)] = acc[a][b];
}

// ---------------------------------------------------------------------------
// Kernel 2 (fused): blocks [0,GA+GB) compute Gram partials; blocks
// [GA+GB, GA+GB+POSB) compute the positive-pair term. Both phases depend only
// on p/q, so they run concurrently in one dispatch.
// Pos: 4 pairs/wave/iter x 2 statically-unrolled iters, all loads in flight.
// ---------------------------------------------------------------------------
__global__ __launch_bounds__(256) void mid_kernel(
    const float* __restrict__ p_ud, int U, float* __restrict__ PA,
    const float* __restrict__ q_vd, int V, float* __restrict__ PB,
    const float* __restrict__ su, const float* __restrict__ sv,
    const float* __restrict__ h2,
    const int* __restrict__ pu, const int* __restrict__ pi,
    int P, float* __restrict__ out)
{
    if (blockIdx.x < GA) { gram_block(p_ud, U, blockIdx.x, GA, PA); return; }
    if (blockIdx.x < GA + GB) { gram_block(q_vd, V, blockIdx.x - GA, GB, PB); return; }

    // ---- positive-pair part ----
    __shared__ float red[4];
    int lane = threadIdx.x & 63;
    int sl   = lane & 15;
    int sub  = lane >> 4;
    int wId  = (blockIdx.x - (GA + GB)) * 4 + (threadIdx.x >> 6);
    const int NW = POSB * 4;                 // 8192 waves

    float4v h2v = *(const float4v*)(h2 + sl * 4);

    int pid0 = wId * 4 + sub;                // [0, 32768)
    int pid1 = pid0 + NW * 4;                // [32768, 65536)
    bool ok0 = pid0 < P, ok1 = pid1 < P;

    int u0 = 0, v0 = 0, u1 = 0, v1 = 0;
    if (ok0) { u0 = pu[pid0]; v0 = pi[pid0]; }
    if (ok1) { u1 = pu[pid1]; v1 = pi[pid1]; }

    float4v pv0 = (float4v)0.0f, qv0 = (float4v)0.0f;
    float4v pv1 = (float4v)0.0f, qv1 = (float4v)0.0f;
    if (ok0) {
        pv0 = *(const float4v*)(p_ud + (size_t)u0 * DD + sl * 4);
        qv0 = *(const float4v*)(q_vd + (size_t)v0 * DD + sl * 4);
    }
    if (ok1) {
        pv1 = *(const float4v*)(p_ud + (size_t)u1 * DD + sl * 4);
        qv1 = *(const float4v*)(q_vd + (size_t)v1 * DD + sl * 4);
    }

    float d0 = pv0.x * qv0.x * h2v.x + pv0.y * qv0.y * h2v.y
             + pv0.z * qv0.z * h2v.z + pv0.w * qv0.w * h2v.w;
    float d1 = pv1.x * qv1.x * h2v.x + pv1.y * qv1.y * h2v.y
             + pv1.z * qv1.z * h2v.z + pv1.w * qv1.w * h2v.w;
#pragma unroll
    for (int off = 1; off < 16; off <<= 1) {
        d0 += __shfl_xor(d0, off, 64);
        d1 += __shfl_xor(d1, off, 64);
    }

    float acc = 0.0f;
    if (sl == 0) {
        if (ok0) { float y = d0 + su[u0] + sv[v0]; acc += 0.5f * y * y - 2.0f * y; }
        if (ok1) { float y = d1 + su[u1] + sv[v1]; acc += 0.5f * y * y - 2.0f * y; }
    }
    acc += __shfl_xor(acc, 16, 64);
    acc += __shfl_xor(acc, 32, 64);
    if (lane == 0) red[threadIdx.x >> 6] = acc;
    __syncthreads();
    if (threadIdx.x == 0)
        atomicAdd(out, red[0] + red[1] + red[2] + red[3]);
}

// ---------------------------------------------------------------------------
// Kernel 3: reduce gram partials + negative term.
// ---------------------------------------------------------------------------
__global__ __launch_bounds__(256) void neg_reduce_kernel(
    const float* __restrict__ PA, const float* __restrict__ PB,
    const float* __restrict__ h2, float* __restrict__ out)
{
    __shared__ float red[4];
    int e = blockIdx.x * 256 + threadIdx.x;   // 0..4095
    float a = 0.0f, b = 0.0f;
    for (int k = 0; k < GA; ++k) a += PA[(size_t)k * (DD * DD) + e];
    for (int k = 0; k < GB; ++k) b += PB[(size_t)k * (DD * DD) + e];
    int i = e >> 6, j = e & 63;
    float acc = h2[i] * h2[j] * a * b;
#pragma unroll
    for (int off = 32; off > 0; off >>= 1)
        acc += __shfl_xor(acc, off, 64);
    int lane = threadIdx.x & 63;
    if (lane == 0) red[threadIdx.x >> 6] = acc;
    __syncthreads();
    if (threadIdx.x == 0)
        atomicAdd(out, 0.5f * (red[0] + red[1] + red[2] + red[3]));
}

extern "C" void kernel_launch(void* const* d_in, const int* in_sizes, int n_in,
                              void* d_out, int out_size, void* d_ws, size_t ws_size,
                              hipStream_t stream)
{
    const float* user_emb = (const float*)d_in[0];
    const float* item_emb = (const float*)d_in[1];
    const float* w_user   = (const float*)d_in[2];
    const float* w_item   = (const float*)d_in[3];
    const float* bias     = (const float*)d_in[4];
    const float* h1       = (const float*)d_in[5];
    const float* h2       = (const float*)d_in[6];
    const int*   ufeat    = (const int*)d_in[7];
    const int*   ifeat    = (const int*)d_in[8];
    const int*   pu       = (const int*)d_in[9];
    const int*   pi       = (const int*)d_in[10];

    const int U = in_sizes[7] / FD;
    const int V = in_sizes[8] / FD;
    const int P = in_sizes[9];

    float* ws = (float*)d_ws;
    size_t off = 0;
    float* p_ud = ws + off; off += (size_t)U * DD;
    float* su   = ws + off; off += (size_t)U;          off = (off + 63) & ~(size_t)63;
    float* q_vd = ws + off; off += (size_t)V * DD;
    float* sv   = ws + off; off += (size_t)V;          off = (off + 63) & ~(size_t)63;
    float* PA   = ws + off; off += (size_t)GA * DD * DD;
    float* PB   = ws + off; off += (size_t)GB * DD * DD;

    float* out = (float*)d_out;
    hipMemsetAsync(out, 0, sizeof(float) * out_size, stream);

    int nent = U + V;
    entity_kernel<<<(nent + 3) / 4, 256, 0, stream>>>(
        user_emb, item_emb, w_user, w_item, bias, h1,
        ufeat, ifeat, p_ud, su, q_vd, sv, U, V);

    mid_kernel<<<GA + GB + POSB, 256, 0, stream>>>(
        p_ud, U, PA, q_vd, V, PB, su, sv, h2, pu, pi, P, out);

    neg_reduce_kernel<<<16, 256, 0, stream>>>(PA, PB, h2, out);
}

// Round 5
// 175.455 us; speedup vs baseline: 2.3731x; 1.1127x over previous
//
#include <hip/hip_runtime.h>

#define FD 20
#define DD 64

#define GA 128    // gram partial blocks for A (users)
#define GB 384    // gram partial blocks for B (items)
#define POSB 2048 // pos blocks in fused mid kernel
#define NEGB 16   // neg reduce blocks

typedef float float4v __attribute__((ext_vector_type(4)));

// ---------------------------------------------------------------------------
// Kernel 1: per-entity FM terms. One wave per entity.
// Lane l = 16*grp + c: loads float4 chunk c of features {grp+4i, i=0..4}.
// 5 independent dwordx4 gathers per lane (per-lane addresses -> no scalar
// waterfall), then shfl_xor(16,32) to reduce across the 4 feature groups.
// ---------------------------------------------------------------------------
__global__ __launch_bounds__(256, 4) void entity_kernel(
    const float* __restrict__ user_emb, const float* __restrict__ item_emb,
    const float* __restrict__ w_user, const float* __restrict__ w_item,
    const float* __restrict__ bias, const float* __restrict__ h1,
    const int* __restrict__ ufeat, const int* __restrict__ ifeat,
    float* __restrict__ p_ud, float* __restrict__ su,
    float* __restrict__ q_vd, float* __restrict__ sv,
    int U, int V)
{
    int wid  = (int)((blockIdx.x * blockDim.x + threadIdx.x) >> 6);
    int lane = threadIdx.x & 63;
    if (wid >= U + V) return;

    const float* emb; const float* wv; const int* fidx; float extra;
    float* srow; float* sc;
    if (wid < U) {
        emb = user_emb; wv = w_user; fidx = ufeat + (size_t)wid * FD;
        extra = bias[0]; srow = p_ud + (size_t)wid * DD; sc = su + wid;
    } else {
        int m = wid - U;
        emb = item_emb; wv = w_item; fidx = ifeat + (size_t)m * FD;
        extra = 0.0f; srow = q_vd + (size_t)m * DD; sc = sv + m;
    }

    // lanes 0..19 load the 20 feature indices + their w values (coalesced)
    int myidx = 0; float myw = 0.0f;
    if (lane < FD) {
        myidx = fidx[lane];
        myw   = wv[myidx];
    }

    int grp = lane >> 4;     // 0..3: feature group
    int c   = lane & 15;     // float4 chunk within the 64-dim row

    // distribute the 5 feature indices this lane needs (independent shuffles)
    int fx[5];
#pragma unroll
    for (int i = 0; i < 5; ++i)
        fx[i] = __shfl(myidx, grp + 4 * i, 64);

    // 5 independent 16B gathers, all in flight simultaneously
    float4v g[5];
#pragma unroll
    for (int i = 0; i < 5; ++i)
        g[i] = *(const float4v*)(emb + (size_t)fx[i] * DD + c * 4);

    float4v s4  = g[0] + g[1] + g[2] + g[3] + g[4];
    float4v ss4 = g[0]*g[0] + g[1]*g[1] + g[2]*g[2] + g[3]*g[3] + g[4]*g[4];

    // reduce across the 4 feature groups (lanes c, c+16, c+32, c+48)
#pragma unroll
    for (int off = 16; off <= 32; off <<= 1) {
        float4v t, u;
        t.x = __shfl_xor(s4.x,  off, 64); t.y = __shfl_xor(s4.y,  off, 64);
        t.z = __shfl_xor(s4.z,  off, 64); t.w = __shfl_xor(s4.w,  off, 64);
        u.x = __shfl_xor(ss4.x, off, 64); u.y = __shfl_xor(ss4.y, off, 64);
        u.z = __shfl_xor(ss4.z, off, 64); u.w = __shfl_xor(ss4.w, off, 64);
        s4 += t; ss4 += u;
    }

    // bi-interaction dot with h1 (group 0 only, to avoid 4x double-count)
    float part = myw;                       // lanes >= 20: myw = 0
    if (grp == 0) {
        float4v h14 = *(const float4v*)(h1 + c * 4);
        float4v bi4 = 0.5f * (s4 * s4 - ss4);
        part += bi4.x*h14.x + bi4.y*h14.y + bi4.z*h14.z + bi4.w*h14.w;
        *(float4v*)(srow + c * 4) = s4;     // 16 lanes x 16B = 256B coalesced
    }

#pragma unroll
    for (int off = 1; off <= 32; off <<= 1)
        part += __shfl_xor(part, off, 64);

    if (lane == 0) *sc = part + extra;
}

// ---------------------------------------------------------------------------
// Gram partial block: 64-row LDS tiles, 4x4 register tile/thread, plain store.
// ---------------------------------------------------------------------------
__device__ __forceinline__ void gram_block(
    const float* __restrict__ M, int nrows, int bid, int nblk,
    float* __restrict__ Gpart)
{
    __shared__ float tile[64][64];
    int t  = threadIdx.x;          // 0..255
    int i0 = (t & 15) << 2;
    int j0 = (t >> 4) << 2;
    float acc[4][4] = {};

    int ntiles = (nrows + 63) >> 6;
    for (int tt = bid; tt < ntiles; tt += nblk) {
        int row0 = tt << 6;
        __syncthreads();
#pragma unroll
        for (int k = 0; k < 4; ++k) {
            int fi = t + k * 256;
            int r  = fi >> 4;
            int c4 = (fi & 15) << 2;
            float4v v = (float4v)0.0f;
            if (row0 + r < nrows)
                v = *(const float4v*)(M + (size_t)(row0 + r) * DD + c4);
            *(float4v*)&tile[r][c4] = v;
        }
        __syncthreads();
        for (int n = 0; n < 64; ++n) {
            float4v va = *(const float4v*)&tile[n][i0];
            float4v vb = *(const float4v*)&tile[n][j0];
#pragma unroll
            for (int a = 0; a < 4; ++a)
#pragma unroll
                for (int b = 0; b < 4; ++b)
                    acc[a][b] += va[a] * vb[b];
        }
    }
    float* out = Gpart + (size_t)bid * (DD * DD);
#pragma unroll
    for (int a = 0; a < 4; ++a)
#pragma unroll
        for (int b = 0; b < 4; ++b)
            out[(i0 + a) * DD + (j0 + b)] = acc[a][b];
}

// ---------------------------------------------------------------------------
// Kernel 2 (fused): blocks [0,GA+GB) Gram partials; [GA+GB, +POSB) pos pairs.
// Pos blocks write a per-block partial (NO atomics).
// ---------------------------------------------------------------------------
__global__ __launch_bounds__(256) void mid_kernel(
    const float* __restrict__ p_ud, int U, float* __restrict__ PA,
    const float* __restrict__ q_vd, int V, float* __restrict__ PB,
    const float* __restrict__ su, const float* __restrict__ sv,
    const float* __restrict__ h2,
    const int* __restrict__ pu, const int* __restrict__ pi,
    int P, float* __restrict__ posPart)
{
    if (blockIdx.x < GA) { gram_block(p_ud, U, blockIdx.x, GA, PA); return; }
    if (blockIdx.x < GA + GB) { gram_block(q_vd, V, blockIdx.x - GA, GB, PB); return; }

    // ---- positive-pair part ----
    __shared__ float red[4];
    int lane = threadIdx.x & 63;
    int sl   = lane & 15;
    int sub  = lane >> 4;
    int pb   = blockIdx.x - (GA + GB);
    int wId  = pb * 4 + (threadIdx.x >> 6);
    const int NW = POSB * 4;                 // 8192 waves

    float4v h2v = *(const float4v*)(h2 + sl * 4);

    int pid0 = wId * 4 + sub;                // [0, 32768)
    int pid1 = pid0 + NW * 4;                // [32768, 65536)
    bool ok0 = pid0 < P, ok1 = pid1 < P;

    int u0 = 0, v0 = 0, u1 = 0, v1 = 0;
    if (ok0) { u0 = pu[pid0]; v0 = pi[pid0]; }
    if (ok1) { u1 = pu[pid1]; v1 = pi[pid1]; }

    float4v pv0 = (float4v)0.0f, qv0 = (float4v)0.0f;
    float4v pv1 = (float4v)0.0f, qv1 = (float4v)0.0f;
    if (ok0) {
        pv0 = *(const float4v*)(p_ud + (size_t)u0 * DD + sl * 4);
        qv0 = *(const float4v*)(q_vd + (size_t)v0 * DD + sl * 4);
    }
    if (ok1) {
        pv1 = *(const float4v*)(p_ud + (size_t)u1 * DD + sl * 4);
        qv1 = *(const float4v*)(q_vd + (size_t)v1 * DD + sl * 4);
    }

    float d0 = pv0.x * qv0.x * h2v.x + pv0.y * qv0.y * h2v.y
             + pv0.z * qv0.z * h2v.z + pv0.w * qv0.w * h2v.w;
    float d1 = pv1.x * qv1.x * h2v.x + pv1.y * qv1.y * h2v.y
             + pv1.z * qv1.z * h2v.z + pv1.w * qv1.w * h2v.w;
#pragma unroll
    for (int off = 1; off < 16; off <<= 1) {
        d0 += __shfl_xor(d0, off, 64);
        d1 += __shfl_xor(d1, off, 64);
    }

    float acc = 0.0f;
    if (sl == 0) {
        if (ok0) { float y = d0 + su[u0] + sv[v0]; acc += 0.5f * y * y - 2.0f * y; }
        if (ok1) { float y = d1 + su[u1] + sv[v1]; acc += 0.5f * y * y - 2.0f * y; }
    }
    acc += __shfl_xor(acc, 16, 64);
    acc += __shfl_xor(acc, 32, 64);
    if (lane == 0) red[threadIdx.x >> 6] = acc;
    __syncthreads();
    if (threadIdx.x == 0)
        posPart[pb] = red[0] + red[1] + red[2] + red[3];
}

// ---------------------------------------------------------------------------
// Kernel 3: reduce gram partials -> negative term, plus pos partials.
// 16 blocks: thread t owns Gram entry e = b*256+t; block b also folds
// posPart[b*128 .. b*128+127]. 16 atomics total onto zeroed out.
// ---------------------------------------------------------------------------
__global__ __launch_bounds__(256) void neg_reduce_kernel(
    const float* __restrict__ PA, const float* __restrict__ PB,
    const float* __restrict__ h2, const float* __restrict__ posPart,
    float* __restrict__ out)
{
    __shared__ float red[4];
    int e = blockIdx.x * 256 + threadIdx.x;   // 0..4095
    float a = 0.0f, b = 0.0f;
    for (int k = 0; k < GA; ++k) a += PA[(size_t)k * (DD * DD) + e];
    for (int k = 0; k < GB; ++k) b += PB[(size_t)k * (DD * DD) + e];
    int i = e >> 6, j = e & 63;
    float acc = 0.5f * h2[i] * h2[j] * a * b;

    if (threadIdx.x < POSB / NEGB)            // 128 pos partials per block
        acc += posPart[blockIdx.x * (POSB / NEGB) + threadIdx.x];

#pragma unroll
    for (int off = 32; off > 0; off >>= 1)
        acc += __shfl_xor(acc, off, 64);
    int lane = threadIdx.x & 63;
    if (lane == 0) red[threadIdx.x >> 6] = acc;
    __syncthreads();
    if (threadIdx.x == 0)
        atomicAdd(out, red[0] + red[1] + red[2] + red[3]);
}

extern "C" void kernel_launch(void* const* d_in, const int* in_sizes, int n_in,
                              void* d_out, int out_size, void* d_ws, size_t ws_size,
                              hipStream_t stream)
{
    const float* user_emb = (const float*)d_in[0];
    const float* item_emb = (const float*)d_in[1];
    const float* w_user   = (const float*)d_in[2];
    const float* w_item   = (const float*)d_in[3];
    const float* bias     = (const float*)d_in[4];
    const float* h1       = (const float*)d_in[5];
    const float* h2       = (const float*)d_in[6];
    const int*   ufeat    = (const int*)d_in[7];
    const int*   ifeat    = (const int*)d_in[8];
    const int*   pu       = (const int*)d_in[9];
    const int*   pi       = (const int*)d_in[10];

    const int U = in_sizes[7] / FD;
    const int V = in_sizes[8] / FD;
    const int P = in_sizes[9];

    float* ws = (float*)d_ws;
    size_t off = 0;
    float* p_ud = ws + off; off += (size_t)U * DD;
    float* su   = ws + off; off += (size_t)U;          off = (off + 63) & ~(size_t)63;
    float* q_vd = ws + off; off += (size_t)V * DD;
    float* sv   = ws + off; off += (size_t)V;          off = (off + 63) & ~(size_t)63;
    float* PA   = ws + off; off += (size_t)GA * DD * DD;
    float* PB   = ws + off; off += (size_t)GB * DD * DD;
    float* posPart = ws + off; off += (size_t)POSB;

    float* out = (float*)d_out;
    hipMemsetAsync(out, 0, sizeof(float) * out_size, stream);

    int nent = U + V;
    entity_kernel<<<(nent + 3) / 4, 256, 0, stream>>>(
        user_emb, item_emb, w_user, w_item, bias, h1,
        ufeat, ifeat, p_ud, su, q_vd, sv, U, V);

    mid_kernel<<<GA + GB + POSB, 256, 0, stream>>>(
        p_ud, U, PA, q_vd, V, PB, su, sv, h2, pu, pi, P, posPart);

    neg_reduce_kernel<<<NEGB, 256, 0, stream>>>(PA, PB, h2, posPart, out);
}

// Round 6
// 171.445 us; speedup vs baseline: 2.4286x; 1.0234x over previous
//
#include <hip/hip_runtime.h>

#define FD 20
#define DD 64

#define GA 64     // gram partial blocks for A (users)
#define GB 128    // gram partial blocks for B (items)
#define POSB 2048 // pos blocks in fused mid kernel
#define NEGB 16   // neg reduce blocks

typedef float float4v __attribute__((ext_vector_type(4)));
typedef unsigned short ushort4v __attribute__((ext_vector_type(4)));

__device__ __forceinline__ unsigned short f2bf(float f) {
    unsigned u = __float_as_uint(f);
    unsigned r = u + 0x7fffu + ((u >> 16) & 1u);   // round-to-nearest-even
    return (unsigned short)(r >> 16);
}
__device__ __forceinline__ float bf2f(unsigned short h) {
    return __uint_as_float((unsigned)h << 16);
}

// ---------------------------------------------------------------------------
// Kernel 0: fp32 -> bf16 conversion of both embedding tables (streaming).
// i in [0, 2*n4): first n4 float4-groups are user table, rest item table.
// ---------------------------------------------------------------------------
__global__ __launch_bounds__(256) void conv_kernel(
    const float* __restrict__ ue, const float* __restrict__ ie,
    unsigned short* __restrict__ ub, unsigned short* __restrict__ ib,
    int n4)
{
    int i = blockIdx.x * blockDim.x + threadIdx.x;
    if (i >= 2 * n4) return;
    const float4v* src; ushort4v* dst; int k;
    if (i < n4) { src = (const float4v*)ue; dst = (ushort4v*)ub; k = i; }
    else        { src = (const float4v*)ie; dst = (ushort4v*)ib; k = i - n4; }
    float4v v = src[k];
    ushort4v o;
    o.x = f2bf(v.x); o.y = f2bf(v.y); o.z = f2bf(v.z); o.w = f2bf(v.w);
    dst[k] = o;
}

// ---------------------------------------------------------------------------
// Kernel 1: per-entity FM terms, bf16 gathers. One wave per entity.
// Lane l = 16*grp + c: loads ushort4 chunk c (4 dims, 8B) of features
// {grp+4i, i=0..4} -> 5 independent 8B gathers/lane, row = 128B = 2 lines.
// Accumulation in fp32; shfl_xor(16,32) reduces across the 4 feature groups.
// ---------------------------------------------------------------------------
__global__ __launch_bounds__(256, 4) void entity_kernel(
    const unsigned short* __restrict__ user_bf,
    const unsigned short* __restrict__ item_bf,
    const float* __restrict__ w_user, const float* __restrict__ w_item,
    const float* __restrict__ bias, const float* __restrict__ h1,
    const int* __restrict__ ufeat, const int* __restrict__ ifeat,
    float* __restrict__ p_ud, float* __restrict__ su,
    float* __restrict__ q_vd, float* __restrict__ sv,
    int U, int V)
{
    int wid  = (int)((blockIdx.x * blockDim.x + threadIdx.x) >> 6);
    int lane = threadIdx.x & 63;
    if (wid >= U + V) return;

    const unsigned short* emb; const float* wv; const int* fidx; float extra;
    float* srow; float* sc;
    if (wid < U) {
        emb = user_bf; wv = w_user; fidx = ufeat + (size_t)wid * FD;
        extra = bias[0]; srow = p_ud + (size_t)wid * DD; sc = su + wid;
    } else {
        int m = wid - U;
        emb = item_bf; wv = w_item; fidx = ifeat + (size_t)m * FD;
        extra = 0.0f; srow = q_vd + (size_t)m * DD; sc = sv + m;
    }

    // lanes 0..19 load the 20 feature indices + their w values (coalesced)
    int myidx = 0; float myw = 0.0f;
    if (lane < FD) {
        myidx = fidx[lane];
        myw   = wv[myidx];
    }

    int grp = lane >> 4;     // 0..3: feature group
    int c   = lane & 15;     // 4-dim chunk within the 64-dim row

    int fx[5];
#pragma unroll
    for (int i = 0; i < 5; ++i)
        fx[i] = __shfl(myidx, grp + 4 * i, 64);

    // 5 independent 8B gathers, all in flight simultaneously
    ushort4v h[5];
#pragma unroll
    for (int i = 0; i < 5; ++i)
        h[i] = *((const ushort4v*)(emb + (size_t)fx[i] * DD) + c);

    float4v s4 = (float4v)0.0f, ss4 = (float4v)0.0f;
#pragma unroll
    for (int i = 0; i < 5; ++i) {
        float4v g;
        g.x = bf2f(h[i].x); g.y = bf2f(h[i].y);
        g.z = bf2f(h[i].z); g.w = bf2f(h[i].w);
        s4 += g; ss4 += g * g;
    }

    // reduce across the 4 feature groups (lanes c, c+16, c+32, c+48)
#pragma unroll
    for (int off = 16; off <= 32; off <<= 1) {
        float4v t, u;
        t.x = __shfl_xor(s4.x,  off, 64); t.y = __shfl_xor(s4.y,  off, 64);
        t.z = __shfl_xor(s4.z,  off, 64); t.w = __shfl_xor(s4.w,  off, 64);
        u.x = __shfl_xor(ss4.x, off, 64); u.y = __shfl_xor(ss4.y, off, 64);
        u.z = __shfl_xor(ss4.z, off, 64); u.w = __shfl_xor(ss4.w, off, 64);
        s4 += t; ss4 += u;
    }

    float part = myw;                       // lanes >= 20: myw = 0
    if (grp == 0) {
        float4v h14 = *(const float4v*)(h1 + c * 4);
        float4v bi4 = 0.5f * (s4 * s4 - ss4);
        part += bi4.x*h14.x + bi4.y*h14.y + bi4.z*h14.z + bi4.w*h14.w;
        *(float4v*)(srow + c * 4) = s4;     // 16 lanes x 16B = 256B coalesced
    }

#pragma unroll
    for (int off = 1; off <= 32; off <<= 1)
        part += __shfl_xor(part, off, 64);

    if (lane == 0) *sc = part + extra;
}

// ---------------------------------------------------------------------------
// Gram partial block: 64-row LDS tiles, 4x4 register tile/thread, plain store.
// ---------------------------------------------------------------------------
__device__ __forceinline__ void gram_block(
    const float* __restrict__ M, int nrows, int bid, int nblk,
    float* __restrict__ Gpart)
{
    __shared__ float tile[64][64];
    int t  = threadIdx.x;          // 0..255
    int i0 = (t & 15) << 2;
    int j0 = (t >> 4) << 2;
    float acc[4][4] = {};

    int ntiles = (nrows + 63) >> 6;
    for (int tt = bid; tt < ntiles; tt += nblk) {
        int row0 = tt << 6;
        __syncthreads();
#pragma unroll
        for (int k = 0; k < 4; ++k) {
            int fi = t + k * 256;
            int r  = fi >> 4;
            int c4 = (fi & 15) << 2;
            float4v v = (float4v)0.0f;
            if (row0 + r < nrows)
                v = *(const float4v*)(M + (size_t)(row0 + r) * DD + c4);
            *(float4v*)&tile[r][c4] = v;
        }
        __syncthreads();
        for (int n = 0; n < 64; ++n) {
            float4v va = *(const float4v*)&tile[n][i0];
            float4v vb = *(const float4v*)&tile[n][j0];
#pragma unroll
            for (int a = 0; a < 4; ++a)
#pragma unroll
                for (int b = 0; b < 4; ++b)
                    acc[a][b] += va[a] * vb[b];
        }
    }
    float* out = Gpart + (size_t)bid * (DD * DD);
#pragma unroll
    for (int a = 0; a < 4; ++a)
#pragma unroll
        for (int b = 0; b < 4; ++b)
            out[(i0 + a) * DD + (j0 + b)] = acc[a][b];
}

// ---------------------------------------------------------------------------
// Kernel 2 (fused): blocks [0,GA+GB) Gram partials; [GA+GB, +POSB) pos pairs.
// Pos blocks write a per-block partial (NO atomics).
// ---------------------------------------------------------------------------
__global__ __launch_bounds__(256) void mid_kernel(
    const float* __restrict__ p_ud, int U, float* __restrict__ PA,
    const float* __restrict__ q_vd, int V, float* __restrict__ PB,
    const float* __restrict__ su, const float* __restrict__ sv,
    const float* __restrict__ h2,
    const int* __restrict__ pu, const int* __restrict__ pi,
    int P, float* __restrict__ posPart)
{
    if (blockIdx.x < GA) { gram_block(p_ud, U, blockIdx.x, GA, PA); return; }
    if (blockIdx.x < GA + GB) { gram_block(q_vd, V, blockIdx.x - GA, GB, PB); return; }

    // ---- positive-pair part ----
    __shared__ float red[4];
    int lane = threadIdx.x & 63;
    int sl   = lane & 15;
    int sub  = lane >> 4;
    int pb   = blockIdx.x - (GA + GB);
    int wId  = pb * 4 + (threadIdx.x >> 6);
    const int NW = POSB * 4;                 // 8192 waves

    float4v h2v = *(const float4v*)(h2 + sl * 4);

    int pid0 = wId * 4 + sub;                // [0, 32768)
    int pid1 = pid0 + NW * 4;                // [32768, 65536)
    bool ok0 = pid0 < P, ok1 = pid1 < P;

    int u0 = 0, v0 = 0, u1 = 0, v1 = 0;
    if (ok0) { u0 = pu[pid0]; v0 = pi[pid0]; }
    if (ok1) { u1 = pu[pid1]; v1 = pi[pid1]; }

    float4v pv0 = (float4v)0.0f, qv0 = (float4v)0.0f;
    float4v pv1 = (float4v)0.0f, qv1 = (float4v)0.0f;
    if (ok0) {
        pv0 = *(const float4v*)(p_ud + (size_t)u0 * DD + sl * 4);
        qv0 = *(const float4v*)(q_vd + (size_t)v0 * DD + sl * 4);
    }
    if (ok1) {
        pv1 = *(const float4v*)(p_ud + (size_t)u1 * DD + sl * 4);
        qv1 = *(const float4v*)(q_vd + (size_t)v1 * DD + sl * 4);
    }

    float d0 = pv0.x * qv0.x * h2v.x + pv0.y * qv0.y * h2v.y
             + pv0.z * qv0.z * h2v.z + pv0.w * qv0.w * h2v.w;
    float d1 = pv1.x * qv1.x * h2v.x + pv1.y * qv1.y * h2v.y
             + pv1.z * qv1.z * h2v.z + pv1.w * qv1.w * h2v.w;
#pragma unroll
    for (int off = 1; off < 16; off <<= 1) {
        d0 += __shfl_xor(d0, off, 64);
        d1 += __shfl_xor(d1, off, 64);
    }

    float acc = 0.0f;
    if (sl == 0) {
        if (ok0) { float y = d0 + su[u0] + sv[v0]; acc += 0.5f * y * y - 2.0f * y; }
        if (ok1) { float y = d1 + su[u1] + sv[v1]; acc += 0.5f * y * y - 2.0f * y; }
    }
    acc += __shfl_xor(acc, 16, 64);
    acc += __shfl_xor(acc, 32, 64);
    if (lane == 0) red[threadIdx.x >> 6] = acc;
    __syncthreads();
    if (threadIdx.x == 0)
        posPart[pb] = red[0] + red[1] + red[2] + red[3];
}

// ---------------------------------------------------------------------------
// Kernel 3: reduce gram partials -> negative term, plus pos partials.
// 16 blocks x 256 threads; thread t owns Gram entry e = b*256+t, k-loops
// unrolled x8 for memory-level parallelism. 16 atomics total onto zeroed out.
// ---------------------------------------------------------------------------
__global__ __launch_bounds__(256) void neg_reduce_kernel(
    const float* __restrict__ PA, const float* __restrict__ PB,
    const float* __restrict__ h2, const float* __restrict__ posPart,
    float* __restrict__ out)
{
    __shared__ float red[4];
    int e = blockIdx.x * 256 + threadIdx.x;   // 0..4095
    float a = 0.0f, b = 0.0f;
#pragma unroll 8
    for (int k = 0; k < GA; ++k) a += PA[(size_t)k * (DD * DD) + e];
#pragma unroll 8
    for (int k = 0; k < GB; ++k) b += PB[(size_t)k * (DD * DD) + e];
    int i = e >> 6, j = e & 63;
    float acc = 0.5f * h2[i] * h2[j] * a * b;

    if (threadIdx.x < POSB / NEGB)            // 128 pos partials per block
        acc += posPart[blockIdx.x * (POSB / NEGB) + threadIdx.x];

#pragma unroll
    for (int off = 32; off > 0; off >>= 1)
        acc += __shfl_xor(acc, off, 64);
    int lane = threadIdx.x & 63;
    if (lane == 0) red[threadIdx.x >> 6] = acc;
    __syncthreads();
    if (threadIdx.x == 0)
        atomicAdd(out, red[0] + red[1] + red[2] + red[3]);
}

extern "C" void kernel_launch(void* const* d_in, const int* in_sizes, int n_in,
                              void* d_out, int out_size, void* d_ws, size_t ws_size,
                              hipStream_t stream)
{
    const float* user_emb = (const float*)d_in[0];
    const float* item_emb = (const float*)d_in[1];
    const float* w_user   = (const float*)d_in[2];
    const float* w_item   = (const float*)d_in[3];
    const float* bias     = (const float*)d_in[4];
    const float* h1       = (const float*)d_in[5];
    const float* h2       = (const float*)d_in[6];
    const int*   ufeat    = (const int*)d_in[7];
    const int*   ifeat    = (const int*)d_in[8];
    const int*   pu       = (const int*)d_in[9];
    const int*   pi       = (const int*)d_in[10];

    const int NF = in_sizes[0] / DD;
    const int U  = in_sizes[7] / FD;
    const int V  = in_sizes[8] / FD;
    const int P  = in_sizes[9];

    float* ws = (float*)d_ws;
    size_t off = 0;
    float* p_ud = ws + off; off += (size_t)U * DD;
    float* su   = ws + off; off += (size_t)U;          off = (off + 63) & ~(size_t)63;
    float* q_vd = ws + off; off += (size_t)V * DD;
    float* sv   = ws + off; off += (size_t)V;          off = (off + 63) & ~(size_t)63;
    float* PA   = ws + off; off += (size_t)GA * DD * DD;
    float* PB   = ws + off; off += (size_t)GB * DD * DD;
    float* posPart = ws + off; off += (size_t)POSB;    off = (off + 63) & ~(size_t)63;
    unsigned short* ubf = (unsigned short*)(ws + off); off += (size_t)NF * DD / 2;
    unsigned short* ibf = (unsigned short*)(ws + off); off += (size_t)NF * DD / 2;

    float* out = (float*)d_out;
    hipMemsetAsync(out, 0, sizeof(float) * out_size, stream);

    int n4 = NF * DD / 4;
    conv_kernel<<<(2 * n4 + 255) / 256, 256, 0, stream>>>(
        user_emb, item_emb, ubf, ibf, n4);

    int nent = U + V;
    entity_kernel<<<(nent + 3) / 4, 256, 0, stream>>>(
        ubf, ibf, w_user, w_item, bias, h1,
        ufeat, ifeat, p_ud, su, q_vd, sv, U, V);

    mid_kernel<<<GA + GB + POSB, 256, 0, stream>>>(
        p_ud, U, PA, q_vd, V, PB, su, sv, h2, pu, pi, P, posPart);

    neg_reduce_kernel<<<NEGB, 256, 0, stream>>>(PA, PB, h2, posPart, out);
}

// Round 7
// 164.795 us; speedup vs baseline: 2.5266x; 1.0404x over previous
//
#include <hip/hip_runtime.h>

#define FD 20
#define DD 64

#define GA 64     // gram partial blocks for A (users)
#define GB 128    // gram partial blocks for B (items)
#define POSB 2048 // pos blocks in fused mid kernel
#define NEGB 64   // neg reduce blocks (one Gram row each)

typedef float float4v __attribute__((ext_vector_type(4)));
typedef unsigned short ushort4v __attribute__((ext_vector_type(4)));

__device__ __forceinline__ unsigned short f2bf(float f) {
    unsigned u = __float_as_uint(f);
    unsigned r = u + 0x7fffu + ((u >> 16) & 1u);   // round-to-nearest-even
    return (unsigned short)(r >> 16);
}
__device__ __forceinline__ float bf2f(unsigned short h) {
    return __uint_as_float((unsigned)h << 16);
}

// ---------------------------------------------------------------------------
// Kernel 0: fp32 -> bf16 conversion of both embedding tables (streaming),
// plus zero-init of d_out (replaces the memset dispatch).
// ---------------------------------------------------------------------------
__global__ __launch_bounds__(256) void conv_kernel(
    const float* __restrict__ ue, const float* __restrict__ ie,
    unsigned short* __restrict__ ub, unsigned short* __restrict__ ib,
    int n4, float* __restrict__ out, int out_size)
{
    int i = blockIdx.x * blockDim.x + threadIdx.x;
    if (i < out_size) out[i] = 0.0f;
    if (i >= 2 * n4) return;
    const float4v* src; ushort4v* dst; int k;
    if (i < n4) { src = (const float4v*)ue; dst = (ushort4v*)ub; k = i; }
    else        { src = (const float4v*)ie; dst = (ushort4v*)ib; k = i - n4; }
    float4v v = src[k];
    ushort4v o;
    o.x = f2bf(v.x); o.y = f2bf(v.y); o.z = f2bf(v.z); o.w = f2bf(v.w);
    dst[k] = o;
}

// ---------------------------------------------------------------------------
// Kernel 1: per-entity FM terms, bf16 gathers. One wave per entity.
// Lane l = 16*grp + c: loads ushort4 chunk c (4 dims, 8B) of features
// {grp+4i, i=0..4} -> 5 independent 8B gathers/lane, row = 128B.
// Accumulation in fp32; shfl_xor(16,32) reduces across the 4 feature groups.
// ---------------------------------------------------------------------------
__global__ __launch_bounds__(256, 4) void entity_kernel(
    const unsigned short* __restrict__ user_bf,
    const unsigned short* __restrict__ item_bf,
    const float* __restrict__ w_user, const float* __restrict__ w_item,
    const float* __restrict__ bias, const float* __restrict__ h1,
    const int* __restrict__ ufeat, const int* __restrict__ ifeat,
    float* __restrict__ p_ud, float* __restrict__ su,
    float* __restrict__ q_vd, float* __restrict__ sv,
    int U, int V)
{
    int wid  = (int)((blockIdx.x * blockDim.x + threadIdx.x) >> 6);
    int lane = threadIdx.x & 63;
    if (wid >= U + V) return;

    const unsigned short* emb; const float* wv; const int* fidx; float extra;
    float* srow; float* sc;
    if (wid < U) {
        emb = user_bf; wv = w_user; fidx = ufeat + (size_t)wid * FD;
        extra = bias[0]; srow = p_ud + (size_t)wid * DD; sc = su + wid;
    } else {
        int m = wid - U;
        emb = item_bf; wv = w_item; fidx = ifeat + (size_t)m * FD;
        extra = 0.0f; srow = q_vd + (size_t)m * DD; sc = sv + m;
    }

    // lanes 0..19 load the 20 feature indices + their w values (coalesced)
    int myidx = 0; float myw = 0.0f;
    if (lane < FD) {
        myidx = fidx[lane];
        myw   = wv[myidx];
    }

    int grp = lane >> 4;     // 0..3: feature group
    int c   = lane & 15;     // 4-dim chunk within the 64-dim row

    int fx[5];
#pragma unroll
    for (int i = 0; i < 5; ++i)
        fx[i] = __shfl(myidx, grp + 4 * i, 64);

    // 5 independent 8B gathers, all in flight simultaneously
    ushort4v h[5];
#pragma unroll
    for (int i = 0; i < 5; ++i)
        h[i] = *((const ushort4v*)(emb + (size_t)fx[i] * DD) + c);

    float4v s4 = (float4v)0.0f, ss4 = (float4v)0.0f;
#pragma unroll
    for (int i = 0; i < 5; ++i) {
        float4v g;
        g.x = bf2f(h[i].x); g.y = bf2f(h[i].y);
        g.z = bf2f(h[i].z); g.w = bf2f(h[i].w);
        s4 += g; ss4 += g * g;
    }

    // reduce across the 4 feature groups (lanes c, c+16, c+32, c+48)
#pragma unroll
    for (int off = 16; off <= 32; off <<= 1) {
        float4v t, u;
        t.x = __shfl_xor(s4.x,  off, 64); t.y = __shfl_xor(s4.y,  off, 64);
        t.z = __shfl_xor(s4.z,  off, 64); t.w = __shfl_xor(s4.w,  off, 64);
        u.x = __shfl_xor(ss4.x, off, 64); u.y = __shfl_xor(ss4.y, off, 64);
        u.z = __shfl_xor(ss4.z, off, 64); u.w = __shfl_xor(ss4.w, off, 64);
        s4 += t; ss4 += u;
    }

    float part = myw;                       // lanes >= 20: myw = 0
    if (grp == 0) {
        float4v h14 = *(const float4v*)(h1 + c * 4);
        float4v bi4 = 0.5f * (s4 * s4 - ss4);
        part += bi4.x*h14.x + bi4.y*h14.y + bi4.z*h14.z + bi4.w*h14.w;
        *(float4v*)(srow + c * 4) = s4;     // 16 lanes x 16B = 256B coalesced
    }

#pragma unroll
    for (int off = 1; off <= 32; off <<= 1)
        part += __shfl_xor(part, off, 64);

    if (lane == 0) *sc = part + extra;
}

// ---------------------------------------------------------------------------
// Gram partial block: 64-row LDS tiles, 4x4 register tile/thread, plain store.
// ---------------------------------------------------------------------------
__device__ __forceinline__ void gram_block(
    const float* __restrict__ M, int nrows, int bid, int nblk,
    float* __restrict__ Gpart)
{
    __shared__ float tile[64][64];
    int t  = threadIdx.x;          // 0..255
    int i0 = (t & 15) << 2;
    int j0 = (t >> 4) << 2;
    float acc[4][4] = {};

    int ntiles = (nrows + 63) >> 6;
    for (int tt = bid; tt < ntiles; tt += nblk) {
        int row0 = tt << 6;
        __syncthreads();
#pragma unroll
        for (int k = 0; k < 4; ++k) {
            int fi = t + k * 256;
            int r  = fi >> 4;
            int c4 = (fi & 15) << 2;
            float4v v = (float4v)0.0f;
            if (row0 + r < nrows)
                v = *(const float4v*)(M + (size_t)(row0 + r) * DD + c4);
            *(float4v*)&tile[r][c4] = v;
        }
        __syncthreads();
        for (int n = 0; n < 64; ++n) {
            float4v va = *(const float4v*)&tile[n][i0];
            float4v vb = *(const float4v*)&tile[n][j0];
#pragma unroll
            for (int a = 0; a < 4; ++a)
#pragma unroll
                for (int b = 0; b < 4; ++b)
                    acc[a][b] += va[a] * vb[b];
        }
    }
    float* out = Gpart + (size_t)bid * (DD * DD);
#pragma unroll
    for (int a = 0; a < 4; ++a)
#pragma unroll
        for (int b = 0; b < 4; ++b)
            out[(i0 + a) * DD + (j0 + b)] = acc[a][b];
}

// ---------------------------------------------------------------------------
// Kernel 2 (fused): blocks [0,GA+GB) Gram partials; [GA+GB, +POSB) pos pairs.
// Pos blocks write a per-block partial (NO atomics).
// ---------------------------------------------------------------------------
__global__ __launch_bounds__(256) void mid_kernel(
    const float* __restrict__ p_ud, int U, float* __restrict__ PA,
    const float* __restrict__ q_vd, int V, float* __restrict__ PB,
    const float* __restrict__ su, const float* __restrict__ sv,
    const float* __restrict__ h2,
    const int* __restrict__ pu, const int* __restrict__ pi,
    int P, float* __restrict__ posPart)
{
    if (blockIdx.x < GA) { gram_block(p_ud, U, blockIdx.x, GA, PA); return; }
    if (blockIdx.x < GA + GB) { gram_block(q_vd, V, blockIdx.x - GA, GB, PB); return; }

    // ---- positive-pair part ----
    __shared__ float red[4];
    int lane = threadIdx.x & 63;
    int sl   = lane & 15;
    int sub  = lane >> 4;
    int pb   = blockIdx.x - (GA + GB);
    int wId  = pb * 4 + (threadIdx.x >> 6);
    const int NW = POSB * 4;                 // 8192 waves

    float4v h2v = *(const float4v*)(h2 + sl * 4);

    int pid0 = wId * 4 + sub;                // [0, 32768)
    int pid1 = pid0 + NW * 4;                // [32768, 65536)
    bool ok0 = pid0 < P, ok1 = pid1 < P;

    int u0 = 0, v0 = 0, u1 = 0, v1 = 0;
    if (ok0) { u0 = pu[pid0]; v0 = pi[pid0]; }
    if (ok1) { u1 = pu[pid1]; v1 = pi[pid1]; }

    float4v pv0 = (float4v)0.0f, qv0 = (float4v)0.0f;
    float4v pv1 = (float4v)0.0f, qv1 = (float4v)0.0f;
    if (ok0) {
        pv0 = *(const float4v*)(p_ud + (size_t)u0 * DD + sl * 4);
        qv0 = *(const float4v*)(q_vd + (size_t)v0 * DD + sl * 4);
    }
    if (ok1) {
        pv1 = *(const float4v*)(p_ud + (size_t)u1 * DD + sl * 4);
        qv1 = *(const float4v*)(q_vd + (size_t)v1 * DD + sl * 4);
    }

    float d0 = pv0.x * qv0.x * h2v.x + pv0.y * qv0.y * h2v.y
             + pv0.z * qv0.z * h2v.z + pv0.w * qv0.w * h2v.w;
    float d1 = pv1.x * qv1.x * h2v.x + pv1.y * qv1.y * h2v.y
             + pv1.z * qv1.z * h2v.z + pv1.w * qv1.w * h2v.w;
#pragma unroll
    for (int off = 1; off < 16; off <<= 1) {
        d0 += __shfl_xor(d0, off, 64);
        d1 += __shfl_xor(d1, off, 64);
    }

    float acc = 0.0f;
    if (sl == 0) {
        if (ok0) { float y = d0 + su[u0] + sv[v0]; acc += 0.5f * y * y - 2.0f * y; }
        if (ok1) { float y = d1 + su[u1] + sv[v1]; acc += 0.5f * y * y - 2.0f * y; }
    }
    acc += __shfl_xor(acc, 16, 64);
    acc += __shfl_xor(acc, 32, 64);
    if (lane == 0) red[threadIdx.x >> 6] = acc;
    __syncthreads();
    if (threadIdx.x == 0)
        posPart[pb] = red[0] + red[1] + red[2] + red[3];
}

// ---------------------------------------------------------------------------
// Kernel 3: reduce gram partials -> negative term, plus pos partials.
// NEGB=64 blocks; block b owns Gram row i=b (64 entries e=b*64+l).
// The 4 waves split the k-range (coalesced 256B loads), LDS-combine the
// A/B sums BEFORE the a*b product. Wave 1 folds 32 pos partials.
// One atomic per block (64 total).
// ---------------------------------------------------------------------------
__global__ __launch_bounds__(256) void neg_reduce_kernel(
    const float* __restrict__ PA, const float* __restrict__ PB,
    const float* __restrict__ h2, const float* __restrict__ posPart,
    float* __restrict__ out)
{
    __shared__ float sA[4][64], sB[4][64];
    __shared__ float sPos;
    int t  = threadIdx.x;
    int l  = t & 63;
    int ch = t >> 6;                       // k-chunk 0..3
    int e  = blockIdx.x * 64 + l;          // Gram entry, i=blockIdx.x, j=l

    float a = 0.0f, b = 0.0f;
#pragma unroll
    for (int k = 0; k < GA / 4; ++k)       // 16 coalesced loads
        a += PA[(size_t)(ch * (GA / 4) + k) * (DD * DD) + e];
#pragma unroll
    for (int k = 0; k < GB / 4; ++k)       // 32 coalesced loads
        b += PB[(size_t)(ch * (GB / 4) + k) * (DD * DD) + e];
    sA[ch][l] = a;
    sB[ch][l] = b;

    if (ch == 1) {                         // wave 1: fold 32 pos partials
        float p = (l < POSB / NEGB) ? posPart[blockIdx.x * (POSB / NEGB) + l] : 0.0f;
#pragma unroll
        for (int off = 1; off <= 32; off <<= 1)
            p += __shfl_xor(p, off, 64);
        if (l == 0) sPos = p;
    }
    __syncthreads();

    if (ch == 0) {
        float fa = sA[0][l] + sA[1][l] + sA[2][l] + sA[3][l];
        float fb = sB[0][l] + sB[1][l] + sB[2][l] + sB[3][l];
        float acc = 0.5f * h2[blockIdx.x] * h2[l] * fa * fb;
#pragma unroll
        for (int off = 1; off <= 32; off <<= 1)
            acc += __shfl_xor(acc, off, 64);
        if (l == 0)
            atomicAdd(out, acc + sPos);
    }
}

extern "C" void kernel_launch(void* const* d_in, const int* in_sizes, int n_in,
                              void* d_out, int out_size, void* d_ws, size_t ws_size,
                              hipStream_t stream)
{
    const float* user_emb = (const float*)d_in[0];
    const float* item_emb = (const float*)d_in[1];
    const float* w_user   = (const float*)d_in[2];
    const float* w_item   = (const float*)d_in[3];
    const float* bias     = (const float*)d_in[4];
    const float* h1       = (const float*)d_in[5];
    const float* h2       = (const float*)d_in[6];
    const int*   ufeat    = (const int*)d_in[7];
    const int*   ifeat    = (const int*)d_in[8];
    const int*   pu       = (const int*)d_in[9];
    const int*   pi       = (const int*)d_in[10];

    const int NF = in_sizes[0] / DD;
    const int U  = in_sizes[7] / FD;
    const int V  = in_sizes[8] / FD;
    const int P  = in_sizes[9];

    float* ws = (float*)d_ws;
    size_t off = 0;
    float* p_ud = ws + off; off += (size_t)U * DD;
    float* su   = ws + off; off += (size_t)U;          off = (off + 63) & ~(size_t)63;
    float* q_vd = ws + off; off += (size_t)V * DD;
    float* sv   = ws + off; off += (size_t)V;          off = (off + 63) & ~(size_t)63;
    float* PA   = ws + off; off += (size_t)GA * DD * DD;
    float* PB   = ws + off; off += (size_t)GB * DD * DD;
    float* posPart = ws + off; off += (size_t)POSB;    off = (off + 63) & ~(size_t)63;
    unsigned short* ubf = (unsigned short*)(ws + off); off += (size_t)NF * DD / 2;
    unsigned short* ibf = (unsigned short*)(ws + off); off += (size_t)NF * DD / 2;

    float* out = (float*)d_out;

    int n4 = NF * DD / 4;
    conv_kernel<<<(2 * n4 + 255) / 256, 256, 0, stream>>>(
        user_emb, item_emb, ubf, ibf, n4, out, out_size);

    int nent = U + V;
    entity_kernel<<<(nent + 3) / 4, 256, 0, stream>>>(
        ubf, ibf, w_user, w_item, bias, h1,
        ufeat, ifeat, p_ud, su, q_vd, sv, U, V);

    mid_kernel<<<GA + GB + POSB, 256, 0, stream>>>(
        p_ud, U, PA, q_vd, V, PB, su, sv, h2, pu, pi, P, posPart);

    neg_reduce_kernel<<<NEGB, 256, 0, stream>>>(PA, PB, h2, posPart, out);
}

// Round 8
// 158.717 us; speedup vs baseline: 2.6233x; 1.0383x over previous
//
#include <hip/hip_runtime.h>

#define FD 20
#define DD 64

#define GA 64     // gram partial blocks for A (users)
#define GB 128    // gram partial blocks for B (items)
#define POSB 2048 // pos blocks in fused mid kernel
#define NEGB 64   // neg reduce blocks (one Gram row each)

typedef float float4v __attribute__((ext_vector_type(4)));
typedef unsigned short ushort4v __attribute__((ext_vector_type(4)));
typedef unsigned short ushort8v __attribute__((ext_vector_type(8)));

__device__ __forceinline__ unsigned short f2bf(float f) {
    unsigned u = __float_as_uint(f);
    unsigned r = u + 0x7fffu + ((u >> 16) & 1u);   // round-to-nearest-even
    return (unsigned short)(r >> 16);
}
__device__ __forceinline__ float bf2f(unsigned short h) {
    return __uint_as_float((unsigned)h << 16);
}

// ---------------------------------------------------------------------------
// Kernel 0: fp32 -> bf16 conversion of both embedding tables (streaming),
// plus zero-init of d_out (replaces the memset dispatch).
// ---------------------------------------------------------------------------
__global__ __launch_bounds__(256) void conv_kernel(
    const float* __restrict__ ue, const float* __restrict__ ie,
    unsigned short* __restrict__ ub, unsigned short* __restrict__ ib,
    int n4, float* __restrict__ out, int out_size)
{
    int i = blockIdx.x * blockDim.x + threadIdx.x;
    if (i < out_size) out[i] = 0.0f;
    if (i >= 2 * n4) return;
    const float4v* src; ushort4v* dst; int k;
    if (i < n4) { src = (const float4v*)ue; dst = (ushort4v*)ub; k = i; }
    else        { src = (const float4v*)ie; dst = (ushort4v*)ib; k = i - n4; }
    float4v v = src[k];
    ushort4v o;
    o.x = f2bf(v.x); o.y = f2bf(v.y); o.z = f2bf(v.z); o.w = f2bf(v.w);
    dst[k] = o;
}

// ---------------------------------------------------------------------------
// Kernel 1: per-entity FM terms, bf16 gathers, bf16 p/q output.
// One wave per entity. Lane l = 16*grp + c: loads ushort4 chunk c (4 dims, 8B)
// of features {grp+4i, i=0..4}; fp32 accumulation; shfl_xor(16,32) reduction.
// ---------------------------------------------------------------------------
__global__ __launch_bounds__(256, 4) void entity_kernel(
    const unsigned short* __restrict__ user_bf,
    const unsigned short* __restrict__ item_bf,
    const float* __restrict__ w_user, const float* __restrict__ w_item,
    const float* __restrict__ bias, const float* __restrict__ h1,
    const int* __restrict__ ufeat, const int* __restrict__ ifeat,
    unsigned short* __restrict__ p_bf, float* __restrict__ su,
    unsigned short* __restrict__ q_bf, float* __restrict__ sv,
    int U, int V)
{
    int wid  = (int)((blockIdx.x * blockDim.x + threadIdx.x) >> 6);
    int lane = threadIdx.x & 63;
    if (wid >= U + V) return;

    const unsigned short* emb; const float* wv; const int* fidx; float extra;
    unsigned short* srow; float* sc;
    if (wid < U) {
        emb = user_bf; wv = w_user; fidx = ufeat + (size_t)wid * FD;
        extra = bias[0]; srow = p_bf + (size_t)wid * DD; sc = su + wid;
    } else {
        int m = wid - U;
        emb = item_bf; wv = w_item; fidx = ifeat + (size_t)m * FD;
        extra = 0.0f; srow = q_bf + (size_t)m * DD; sc = sv + m;
    }

    // lanes 0..19 load the 20 feature indices + their w values (coalesced)
    int myidx = 0; float myw = 0.0f;
    if (lane < FD) {
        myidx = fidx[lane];
        myw   = wv[myidx];
    }

    int grp = lane >> 4;     // 0..3: feature group
    int c   = lane & 15;     // 4-dim chunk within the 64-dim row

    int fx[5];
#pragma unroll
    for (int i = 0; i < 5; ++i)
        fx[i] = __shfl(myidx, grp + 4 * i, 64);

    // 5 independent 8B gathers, all in flight simultaneously
    ushort4v h[5];
#pragma unroll
    for (int i = 0; i < 5; ++i)
        h[i] = *((const ushort4v*)(emb + (size_t)fx[i] * DD) + c);

    float4v s4 = (float4v)0.0f, ss4 = (float4v)0.0f;
#pragma unroll
    for (int i = 0; i < 5; ++i) {
        float4v g;
        g.x = bf2f(h[i].x); g.y = bf2f(h[i].y);
        g.z = bf2f(h[i].z); g.w = bf2f(h[i].w);
        s4 += g; ss4 += g * g;
    }

    // reduce across the 4 feature groups (lanes c, c+16, c+32, c+48)
#pragma unroll
    for (int off = 16; off <= 32; off <<= 1) {
        float4v t, u;
        t.x = __shfl_xor(s4.x,  off, 64); t.y = __shfl_xor(s4.y,  off, 64);
        t.z = __shfl_xor(s4.z,  off, 64); t.w = __shfl_xor(s4.w,  off, 64);
        u.x = __shfl_xor(ss4.x, off, 64); u.y = __shfl_xor(ss4.y, off, 64);
        u.z = __shfl_xor(ss4.z, off, 64); u.w = __shfl_xor(ss4.w, off, 64);
        s4 += t; ss4 += u;
    }

    float part = myw;                       // lanes >= 20: myw = 0
    if (grp == 0) {
        float4v h14 = *(const float4v*)(h1 + c * 4);
        float4v bi4 = 0.5f * (s4 * s4 - ss4);
        part += bi4.x*h14.x + bi4.y*h14.y + bi4.z*h14.z + bi4.w*h14.w;
        ushort4v o;
        o.x = f2bf(s4.x); o.y = f2bf(s4.y); o.z = f2bf(s4.z); o.w = f2bf(s4.w);
        *(ushort4v*)(srow + c * 4) = o;     // 16 lanes x 8B = 128B coalesced
    }

#pragma unroll
    for (int off = 1; off <= 32; off <<= 1)
        part += __shfl_xor(part, off, 64);

    if (lane == 0) *sc = part + extra;
}

// ---------------------------------------------------------------------------
// Gram partial block over a bf16 matrix: 64-row LDS tiles (fp32 in LDS),
// 4x4 register tile/thread, plain store of the block's 64x64 partial.
// ---------------------------------------------------------------------------
__device__ __forceinline__ void gram_block(
    const unsigned short* __restrict__ M, int nrows, int bid, int nblk,
    float* __restrict__ Gpart)
{
    __shared__ float tile[64][64];
    int t  = threadIdx.x;          // 0..255
    int i0 = (t & 15) << 2;
    int j0 = (t >> 4) << 2;
    float acc[4][4] = {};

    int ntiles = (nrows + 63) >> 6;
    for (int tt = bid; tt < ntiles; tt += nblk) {
        int row0 = tt << 6;
        __syncthreads();
#pragma unroll
        for (int k = 0; k < 2; ++k) {
            int fi = t + k * 256;              // ushort8 (16B) index in [0,512)
            int r  = fi >> 3;                  // row 0..63
            int c8 = (fi & 7) << 3;            // dim start 0,8,..,56
            ushort8v hv = (ushort8v)0;
            if (row0 + r < nrows)
                hv = *(const ushort8v*)(M + (size_t)(row0 + r) * DD + c8);
            float4v lo, hi;
            lo.x = bf2f(hv[0]); lo.y = bf2f(hv[1]);
            lo.z = bf2f(hv[2]); lo.w = bf2f(hv[3]);
            hi.x = bf2f(hv[4]); hi.y = bf2f(hv[5]);
            hi.z = bf2f(hv[6]); hi.w = bf2f(hv[7]);
            *(float4v*)&tile[r][c8]     = lo;
            *(float4v*)&tile[r][c8 + 4] = hi;
        }
        __syncthreads();
        for (int n = 0; n < 64; ++n) {
            float4v va = *(const float4v*)&tile[n][i0];
            float4v vb = *(const float4v*)&tile[n][j0];
#pragma unroll
            for (int a = 0; a < 4; ++a)
#pragma unroll
                for (int b = 0; b < 4; ++b)
                    acc[a][b] += va[a] * vb[b];
        }
    }
    float* out = Gpart + (size_t)bid * (DD * DD);
#pragma unroll
    for (int a = 0; a < 4; ++a)
#pragma unroll
        for (int b = 0; b < 4; ++b)
            out[(i0 + a) * DD + (j0 + b)] = acc[a][b];
}

// ---------------------------------------------------------------------------
// Kernel 2 (fused): blocks [0,GA+GB) Gram partials; [GA+GB, +POSB) pos pairs.
// Pos blocks write a per-block partial (NO atomics). p/q are bf16.
// ---------------------------------------------------------------------------
__global__ __launch_bounds__(256) void mid_kernel(
    const unsigned short* __restrict__ p_bf, int U, float* __restrict__ PA,
    const unsigned short* __restrict__ q_bf, int V, float* __restrict__ PB,
    const float* __restrict__ su, const float* __restrict__ sv,
    const float* __restrict__ h2,
    const int* __restrict__ pu, const int* __restrict__ pi,
    int P, float* __restrict__ posPart)
{
    if (blockIdx.x < GA) { gram_block(p_bf, U, blockIdx.x, GA, PA); return; }
    if (blockIdx.x < GA + GB) { gram_block(q_bf, V, blockIdx.x - GA, GB, PB); return; }

    // ---- positive-pair part ----
    __shared__ float red[4];
    int lane = threadIdx.x & 63;
    int sl   = lane & 15;
    int sub  = lane >> 4;
    int pb   = blockIdx.x - (GA + GB);
    int wId  = pb * 4 + (threadIdx.x >> 6);
    const int NW = POSB * 4;                 // 8192 waves

    float4v h2v = *(const float4v*)(h2 + sl * 4);

    int pid0 = wId * 4 + sub;                // [0, 32768)
    int pid1 = pid0 + NW * 4;                // [32768, 65536)
    bool ok0 = pid0 < P, ok1 = pid1 < P;

    int u0 = 0, v0 = 0, u1 = 0, v1 = 0;
    if (ok0) { u0 = pu[pid0]; v0 = pi[pid0]; }
    if (ok1) { u1 = pu[pid1]; v1 = pi[pid1]; }

    ushort4v ph0 = (ushort4v)0, qh0 = (ushort4v)0;
    ushort4v ph1 = (ushort4v)0, qh1 = (ushort4v)0;
    if (ok0) {
        ph0 = *(const ushort4v*)(p_bf + (size_t)u0 * DD + sl * 4);
        qh0 = *(const ushort4v*)(q_bf + (size_t)v0 * DD + sl * 4);
    }
    if (ok1) {
        ph1 = *(const ushort4v*)(p_bf + (size_t)u1 * DD + sl * 4);
        qh1 = *(const ushort4v*)(q_bf + (size_t)v1 * DD + sl * 4);
    }

    float d0 = bf2f(ph0.x)*bf2f(qh0.x)*h2v.x + bf2f(ph0.y)*bf2f(qh0.y)*h2v.y
             + bf2f(ph0.z)*bf2f(qh0.z)*h2v.z + bf2f(ph0.w)*bf2f(qh0.w)*h2v.w;
    float d1 = bf2f(ph1.x)*bf2f(qh1.x)*h2v.x + bf2f(ph1.y)*bf2f(qh1.y)*h2v.y
             + bf2f(ph1.z)*bf2f(qh1.z)*h2v.z + bf2f(ph1.w)*bf2f(qh1.w)*h2v.w;
#pragma unroll
    for (int off = 1; off < 16; off <<= 1) {
        d0 += __shfl_xor(d0, off, 64);
        d1 += __shfl_xor(d1, off, 64);
    }

    float acc = 0.0f;
    if (sl == 0) {
        if (ok0) { float y = d0 + su[u0] + sv[v0]; acc += 0.5f * y * y - 2.0f * y; }
        if (ok1) { float y = d1 + su[u1] + sv[v1]; acc += 0.5f * y * y - 2.0f * y; }
    }
    acc += __shfl_xor(acc, 16, 64);
    acc += __shfl_xor(acc, 32, 64);
    if (lane == 0) red[threadIdx.x >> 6] = acc;
    __syncthreads();
    if (threadIdx.x == 0)
        posPart[pb] = red[0] + red[1] + red[2] + red[3];
}

// ---------------------------------------------------------------------------
// Kernel 3: reduce gram partials -> negative term, plus pos partials.
// NEGB=64 blocks; block b owns Gram row i=b. 4 waves split the k-range,
// LDS-combine A/B sums before the a*b product; wave 1 folds 32 pos partials.
// One atomic per block (64 total).
// ---------------------------------------------------------------------------
__global__ __launch_bounds__(256) void neg_reduce_kernel(
    const float* __restrict__ PA, const float* __restrict__ PB,
    const float* __restrict__ h2, const float* __restrict__ posPart,
    float* __restrict__ out)
{
    __shared__ float sA[4][64], sB[4][64];
    __shared__ float sPos;
    int t  = threadIdx.x;
    int l  = t & 63;
    int ch = t >> 6;                       // k-chunk 0..3
    int e  = blockIdx.x * 64 + l;          // Gram entry, i=blockIdx.x, j=l

    float a = 0.0f, b = 0.0f;
#pragma unroll
    for (int k = 0; k < GA / 4; ++k)       // 16 coalesced loads
        a += PA[(size_t)(ch * (GA / 4) + k) * (DD * DD) + e];
#pragma unroll
    for (int k = 0; k < GB / 4; ++k)       // 32 coalesced loads
        b += PB[(size_t)(ch * (GB / 4) + k) * (DD * DD) + e];
    sA[ch][l] = a;
    sB[ch][l] = b;

    if (ch == 1) {                         // wave 1: fold 32 pos partials
        float p = (l < POSB / NEGB) ? posPart[blockIdx.x * (POSB / NEGB) + l] : 0.0f;
#pragma unroll
        for (int off = 1; off <= 32; off <<= 1)
            p += __shfl_xor(p, off, 64);
        if (l == 0) sPos = p;
    }
    __syncthreads();

    if (ch == 0) {
        float fa = sA[0][l] + sA[1][l] + sA[2][l] + sA[3][l];
        float fb = sB[0][l] + sB[1][l] + sB[2][l] + sB[3][l];
        float acc = 0.5f * h2[blockIdx.x] * h2[l] * fa * fb;
#pragma unroll
        for (int off = 1; off <= 32; off <<= 1)
            acc += __shfl_xor(acc, off, 64);
        if (l == 0)
            atomicAdd(out, acc + sPos);
    }
}

extern "C" void kernel_launch(void* const* d_in, const int* in_sizes, int n_in,
                              void* d_out, int out_size, void* d_ws, size_t ws_size,
                              hipStream_t stream)
{
    const float* user_emb = (const float*)d_in[0];
    const float* item_emb = (const float*)d_in[1];
    const float* w_user   = (const float*)d_in[2];
    const float* w_item   = (const float*)d_in[3];
    const float* bias     = (const float*)d_in[4];
    const float* h1       = (const float*)d_in[5];
    const float* h2       = (const float*)d_in[6];
    const int*   ufeat    = (const int*)d_in[7];
    const int*   ifeat    = (const int*)d_in[8];
    const int*   pu       = (const int*)d_in[9];
    const int*   pi       = (const int*)d_in[10];

    const int NF = in_sizes[0] / DD;
    const int U  = in_sizes[7] / FD;
    const int V  = in_sizes[8] / FD;
    const int P  = in_sizes[9];

    float* ws = (float*)d_ws;
    size_t off = 0;
    unsigned short* p_bf = (unsigned short*)(ws + off); off += (size_t)U * DD / 2;
    unsigned short* q_bf = (unsigned short*)(ws + off); off += (size_t)V * DD / 2;
    float* su   = ws + off; off += (size_t)U;          off = (off + 63) & ~(size_t)63;
    float* sv   = ws + off; off += (size_t)V;          off = (off + 63) & ~(size_t)63;
    float* PA   = ws + off; off += (size_t)GA * DD * DD;
    float* PB   = ws + off; off += (size_t)GB * DD * DD;
    float* posPart = ws + off; off += (size_t)POSB;    off = (off + 63) & ~(size_t)63;
    unsigned short* ubf = (unsigned short*)(ws + off); off += (size_t)NF * DD / 2;
    unsigned short* ibf = (unsigned short*)(ws + off); off += (size_t)NF * DD / 2;

    float* out = (float*)d_out;

    int n4 = NF * DD / 4;
    conv_kernel<<<(2 * n4 + 255) / 256, 256, 0, stream>>>(
        user_emb, item_emb, ubf, ibf, n4, out, out_size);

    int nent = U + V;
    entity_kernel<<<(nent + 3) / 4, 256, 0, stream>>>(
        ubf, ibf, w_user, w_item, bias, h1,
        ufeat, ifeat, p_bf, su, q_bf, sv, U, V);

    mid_kernel<<<GA + GB + POSB, 256, 0, stream>>>(
        p_bf, U, PA, q_bf, V, PB, su, sv, h2, pu, pi, P, posPart);

    neg_reduce_kernel<<<NEGB, 256, 0, stream>>>(PA, PB, h2, posPart, out);
}

// Round 9
// 156.492 us; speedup vs baseline: 2.6607x; 1.0142x over previous
//
#include <hip/hip_runtime.h>

#define FD 20
#define DD 64

#define GA 64     // gram partial blocks for A (users)
#define GB 128    // gram partial blocks for B (items)
#define POSB 2048 // pos blocks in fused mid kernel
#define NEGB 64   // neg reduce blocks (one Gram row each)

typedef float float4v __attribute__((ext_vector_type(4)));
typedef unsigned short ushort4v __attribute__((ext_vector_type(4)));
typedef unsigned short ushort8v __attribute__((ext_vector_type(8)));

__device__ __forceinline__ unsigned short f2bf(float f) {
    unsigned u = __float_as_uint(f);
    unsigned r = u + 0x7fffu + ((u >> 16) & 1u);   // round-to-nearest-even
    return (unsigned short)(r >> 16);
}
__device__ __forceinline__ float bf2f(unsigned short h) {
    return __uint_as_float((unsigned)h << 16);
}

// ---------------------------------------------------------------------------
// Kernel 0: fp32 -> fp8 e4m3 (OCP) conversion of both embedding tables via
// HW v_cvt_pk_fp8_f32, plus zero-init of d_out.
// ---------------------------------------------------------------------------
__global__ __launch_bounds__(256) void conv_kernel(
    const float* __restrict__ ue, const float* __restrict__ ie,
    unsigned int* __restrict__ u8, unsigned int* __restrict__ i8,
    int n4, float* __restrict__ out, int out_size)
{
    int i = blockIdx.x * blockDim.x + threadIdx.x;
    if (i < out_size) out[i] = 0.0f;
    if (i >= 2 * n4) return;
    const float4v* src; unsigned int* dst; int k;
    if (i < n4) { src = (const float4v*)ue; dst = u8; k = i; }
    else        { src = (const float4v*)ie; dst = i8; k = i - n4; }
    float4v v = src[k];
    unsigned int p = 0;
    p = __builtin_amdgcn_cvt_pk_fp8_f32(v.x, v.y, p, false);  // bytes 0,1
    p = __builtin_amdgcn_cvt_pk_fp8_f32(v.z, v.w, p, true);   // bytes 2,3
    dst[k] = p;
}

// ---------------------------------------------------------------------------
// Kernel 1: per-entity FM terms, fp8 gathers, bf16 p/q output.
// One wave per entity. Lane l = 16*grp + c: loads uint chunk c (4 dims, 4B)
// of features {grp+4i, i=0..4} -> 5 independent 4B gathers/lane, row = 64B.
// HW fp8->f32 decode; fp32 accumulation; shfl_xor(16,32) reduction.
// ---------------------------------------------------------------------------
__global__ __launch_bounds__(256, 4) void entity_kernel(
    const unsigned char* __restrict__ user_f8,
    const unsigned char* __restrict__ item_f8,
    const float* __restrict__ w_user, const float* __restrict__ w_item,
    const float* __restrict__ bias, const float* __restrict__ h1,
    const int* __restrict__ ufeat, const int* __restrict__ ifeat,
    unsigned short* __restrict__ p_bf, float* __restrict__ su,
    unsigned short* __restrict__ q_bf, float* __restrict__ sv,
    int U, int V)
{
    int wid  = (int)((blockIdx.x * blockDim.x + threadIdx.x) >> 6);
    int lane = threadIdx.x & 63;
    if (wid >= U + V) return;

    const unsigned char* emb; const float* wv; const int* fidx; float extra;
    unsigned short* srow; float* sc;
    if (wid < U) {
        emb = user_f8; wv = w_user; fidx = ufeat + (size_t)wid * FD;
        extra = bias[0]; srow = p_bf + (size_t)wid * DD; sc = su + wid;
    } else {
        int m = wid - U;
        emb = item_f8; wv = w_item; fidx = ifeat + (size_t)m * FD;
        extra = 0.0f; srow = q_bf + (size_t)m * DD; sc = sv + m;
    }

    // lanes 0..19 load the 20 feature indices + their w values (coalesced)
    int myidx = 0; float myw = 0.0f;
    if (lane < FD) {
        myidx = fidx[lane];
        myw   = wv[myidx];
    }

    int grp = lane >> 4;     // 0..3: feature group
    int c   = lane & 15;     // 4-dim chunk within the 64-dim row

    int fx[5];
#pragma unroll
    for (int i = 0; i < 5; ++i)
        fx[i] = __shfl(myidx, grp + 4 * i, 64);

    // 5 independent 4B gathers, all in flight simultaneously
    unsigned int hw[5];
#pragma unroll
    for (int i = 0; i < 5; ++i)
        hw[i] = *((const unsigned int*)(emb + (size_t)fx[i] * DD) + c);

    float4v s4 = (float4v)0.0f, ss4 = (float4v)0.0f;
#pragma unroll
    for (int i = 0; i < 5; ++i) {
        float4v g;
        g.x = __builtin_amdgcn_cvt_f32_fp8(hw[i], 0);
        g.y = __builtin_amdgcn_cvt_f32_fp8(hw[i], 1);
        g.z = __builtin_amdgcn_cvt_f32_fp8(hw[i], 2);
        g.w = __builtin_amdgcn_cvt_f32_fp8(hw[i], 3);
        s4 += g; ss4 += g * g;
    }

    // reduce across the 4 feature groups (lanes c, c+16, c+32, c+48)
#pragma unroll
    for (int off = 16; off <= 32; off <<= 1) {
        float4v t, u;
        t.x = __shfl_xor(s4.x,  off, 64); t.y = __shfl_xor(s4.y,  off, 64);
        t.z = __shfl_xor(s4.z,  off, 64); t.w = __shfl_xor(s4.w,  off, 64);
        u.x = __shfl_xor(ss4.x, off, 64); u.y = __shfl_xor(ss4.y, off, 64);
        u.z = __shfl_xor(ss4.z, off, 64); u.w = __shfl_xor(ss4.w, off, 64);
        s4 += t; ss4 += u;
    }

    float part = myw;                       // lanes >= 20: myw = 0
    if (grp == 0) {
        float4v h14 = *(const float4v*)(h1 + c * 4);
        float4v bi4 = 0.5f * (s4 * s4 - ss4);
        part += bi4.x*h14.x + bi4.y*h14.y + bi4.z*h14.z + bi4.w*h14.w;
        ushort4v o;
        o.x = f2bf(s4.x); o.y = f2bf(s4.y); o.z = f2bf(s4.z); o.w = f2bf(s4.w);
        *(ushort4v*)(srow + c * 4) = o;     // 16 lanes x 8B = 128B coalesced
    }

#pragma unroll
    for (int off = 1; off <= 32; off <<= 1)
        part += __shfl_xor(part, off, 64);

    if (lane == 0) *sc = part + extra;
}

// ---------------------------------------------------------------------------
// Gram partial block over a bf16 matrix: 64-row LDS tiles (fp32 in LDS),
// 4x4 register tile/thread, plain store of the block's 64x64 partial.
// ---------------------------------------------------------------------------
__device__ __forceinline__ void gram_block(
    const unsigned short* __restrict__ M, int nrows, int bid, int nblk,
    float* __restrict__ Gpart)
{
    __shared__ float tile[64][64];
    int t  = threadIdx.x;          // 0..255
    int i0 = (t & 15) << 2;
    int j0 = (t >> 4) << 2;
    float acc[4][4] = {};

    int ntiles = (nrows + 63) >> 6;
    for (int tt = bid; tt < ntiles; tt += nblk) {
        int row0 = tt << 6;
        __syncthreads();
#pragma unroll
        for (int k = 0; k < 2; ++k) {
            int fi = t + k * 256;              // ushort8 (16B) index in [0,512)
            int r  = fi >> 3;                  // row 0..63
            int c8 = (fi & 7) << 3;            // dim start 0,8,..,56
            ushort8v hv = (ushort8v)0;
            if (row0 + r < nrows)
                hv = *(const ushort8v*)(M + (size_t)(row0 + r) * DD + c8);
            float4v lo, hi;
            lo.x = bf2f(hv[0]); lo.y = bf2f(hv[1]);
            lo.z = bf2f(hv[2]); lo.w = bf2f(hv[3]);
            hi.x = bf2f(hv[4]); hi.y = bf2f(hv[5]);
            hi.z = bf2f(hv[6]); hi.w = bf2f(hv[7]);
            *(float4v*)&tile[r][c8]     = lo;
            *(float4v*)&tile[r][c8 + 4] = hi;
        }
        __syncthreads();
        for (int n = 0; n < 64; ++n) {
            float4v va = *(const float4v*)&tile[n][i0];
            float4v vb = *(const float4v*)&tile[n][j0];
#pragma unroll
            for (int a = 0; a < 4; ++a)
#pragma unroll
                for (int b = 0; b < 4; ++b)
                    acc[a][b] += va[a] * vb[b];
        }
    }
    float* out = Gpart + (size_t)bid * (DD * DD);
#pragma unroll
    for (int a = 0; a < 4; ++a)
#pragma unroll
        for (int b = 0; b < 4; ++b)
            out[(i0 + a) * DD + (j0 + b)] = acc[a][b];
}

// ---------------------------------------------------------------------------
// Kernel 2 (fused): blocks [0,GA+GB) Gram partials; [GA+GB, +POSB) pos pairs.
// Pos blocks write a per-block partial (NO atomics). p/q are bf16.
// ---------------------------------------------------------------------------
__global__ __launch_bounds__(256) void mid_kernel(
    const unsigned short* __restrict__ p_bf, int U, float* __restrict__ PA,
    const unsigned short* __restrict__ q_bf, int V, float* __restrict__ PB,
    const float* __restrict__ su, const float* __restrict__ sv,
    const float* __restrict__ h2,
    const int* __restrict__ pu, const int* __restrict__ pi,
    int P, float* __restrict__ posPart)
{
    if (blockIdx.x < GA) { gram_block(p_bf, U, blockIdx.x, GA, PA); return; }
    if (blockIdx.x < GA + GB) { gram_block(q_bf, V, blockIdx.x - GA, GB, PB); return; }

    // ---- positive-pair part ----
    __shared__ float red[4];
    int lane = threadIdx.x & 63;
    int sl   = lane & 15;
    int sub  = lane >> 4;
    int pb   = blockIdx.x - (GA + GB);
    int wId  = pb * 4 + (threadIdx.x >> 6);
    const int NW = POSB * 4;                 // 8192 waves

    float4v h2v = *(const float4v*)(h2 + sl * 4);

    int pid0 = wId * 4 + sub;                // [0, 32768)
    int pid1 = pid0 + NW * 4;                // [32768, 65536)
    bool ok0 = pid0 < P, ok1 = pid1 < P;

    int u0 = 0, v0 = 0, u1 = 0, v1 = 0;
    if (ok0) { u0 = pu[pid0]; v0 = pi[pid0]; }
    if (ok1) { u1 = pu[pid1]; v1 = pi[pid1]; }

    ushort4v ph0 = (ushort4v)0, qh0 = (ushort4v)0;
    ushort4v ph1 = (ushort4v)0, qh1 = (ushort4v)0;
    if (ok0) {
        ph0 = *(const ushort4v*)(p_bf + (size_t)u0 * DD + sl * 4);
        qh0 = *(const ushort4v*)(q_bf + (size_t)v0 * DD + sl * 4);
    }
    if (ok1) {
        ph1 = *(const ushort4v*)(p_bf + (size_t)u1 * DD + sl * 4);
        qh1 = *(const ushort4v*)(q_bf + (size_t)v1 * DD + sl * 4);
    }

    float d0 = bf2f(ph0.x)*bf2f(qh0.x)*h2v.x + bf2f(ph0.y)*bf2f(qh0.y)*h2v.y
             + bf2f(ph0.z)*bf2f(qh0.z)*h2v.z + bf2f(ph0.w)*bf2f(qh0.w)*h2v.w;
    float d1 = bf2f(ph1.x)*bf2f(qh1.x)*h2v.x + bf2f(ph1.y)*bf2f(qh1.y)*h2v.y
             + bf2f(ph1.z)*bf2f(qh1.z)*h2v.z + bf2f(ph1.w)*bf2f(qh1.w)*h2v.w;
#pragma unroll
    for (int off = 1; off < 16; off <<= 1) {
        d0 += __shfl_xor(d0, off, 64);
        d1 += __shfl_xor(d1, off, 64);
    }

    float acc = 0.0f;
    if (sl == 0) {
        if (ok0) { float y = d0 + su[u0] + sv[v0]; acc += 0.5f * y * y - 2.0f * y; }
        if (ok1) { float y = d1 + su[u1] + sv[v1]; acc += 0.5f * y * y - 2.0f * y; }
    }
    acc += __shfl_xor(acc, 16, 64);
    acc += __shfl_xor(acc, 32, 64);
    if (lane == 0) red[threadIdx.x >> 6] = acc;
    __syncthreads();
    if (threadIdx.x == 0)
        posPart[pb] = red[0] + red[1] + red[2] + red[3];
}

// ---------------------------------------------------------------------------
// Kernel 3: reduce gram partials -> negative term, plus pos partials.
// NEGB=64 blocks; block b owns Gram row i=b. 4 waves split the k-range,
// LDS-combine A/B sums before the a*b product; wave 1 folds 32 pos partials.
// One atomic per block (64 total).
// ---------------------------------------------------------------------------
__global__ __launch_bounds__(256) void neg_reduce_kernel(
    const float* __restrict__ PA, const float* __restrict__ PB,
    const float* __restrict__ h2, const float* __restrict__ posPart,
    float* __restrict__ out)
{
    __shared__ float sA[4][64], sB[4][64];
    __shared__ float sPos;
    int t  = threadIdx.x;
    int l  = t & 63;
    int ch = t >> 6;                       // k-chunk 0..3
    int e  = blockIdx.x * 64 + l;          // Gram entry, i=blockIdx.x, j=l

    float a = 0.0f, b = 0.0f;
#pragma unroll
    for (int k = 0; k < GA / 4; ++k)       // 16 coalesced loads
        a += PA[(size_t)(ch * (GA / 4) + k) * (DD * DD) + e];
#pragma unroll
    for (int k = 0; k < GB / 4; ++k)       // 32 coalesced loads
        b += PB[(size_t)(ch * (GB / 4) + k) * (DD * DD) + e];
    sA[ch][l] = a;
    sB[ch][l] = b;

    if (ch == 1) {                         // wave 1: fold 32 pos partials
        float p = (l < POSB / NEGB) ? posPart[blockIdx.x * (POSB / NEGB) + l] : 0.0f;
#pragma unroll
        for (int off = 1; off <= 32; off <<= 1)
            p += __shfl_xor(p, off, 64);
        if (l == 0) sPos = p;
    }
    __syncthreads();

    if (ch == 0) {
        float fa = sA[0][l] + sA[1][l] + sA[2][l] + sA[3][l];
        float fb = sB[0][l] + sB[1][l] + sB[2][l] + sB[3][l];
        float acc = 0.5f * h2[blockIdx.x] * h2[l] * fa * fb;
#pragma unroll
        for (int off = 1; off <= 32; off <<= 1)
            acc += __shfl_xor(acc, off, 64);
        if (l == 0)
            atomicAdd(out, acc + sPos);
    }
}

extern "C" void kernel_launch(void* const* d_in, const int* in_sizes, int n_in,
                              void* d_out, int out_size, void* d_ws, size_t ws_size,
                              hipStream_t stream)
{
    const float* user_emb = (const float*)d_in[0];
    const float* item_emb = (const float*)d_in[1];
    const float* w_user   = (const float*)d_in[2];
    const float* w_item   = (const float*)d_in[3];
    const float* bias     = (const float*)d_in[4];
    const float* h1       = (const float*)d_in[5];
    const float* h2       = (const float*)d_in[6];
    const int*   ufeat    = (const int*)d_in[7];
    const int*   ifeat    = (const int*)d_in[8];
    const int*   pu       = (const int*)d_in[9];
    const int*   pi       = (const int*)d_in[10];

    const int NF = in_sizes[0] / DD;
    const int U  = in_sizes[7] / FD;
    const int V  = in_sizes[8] / FD;
    const int P  = in_sizes[9];

    float* ws = (float*)d_ws;
    size_t off = 0;
    unsigned short* p_bf = (unsigned short*)(ws + off); off += (size_t)U * DD / 2;
    unsigned short* q_bf = (unsigned short*)(ws + off); off += (size_t)V * DD / 2;
    float* su   = ws + off; off += (size_t)U;          off = (off + 63) & ~(size_t)63;
    float* sv   = ws + off; off += (size_t)V;          off = (off + 63) & ~(size_t)63;
    float* PA   = ws + off; off += (size_t)GA * DD * DD;
    float* PB   = ws + off; off += (size_t)GB * DD * DD;
    float* posPart = ws + off; off += (size_t)POSB;    off = (off + 63) & ~(size_t)63;
    unsigned char* uf8 = (unsigned char*)(ws + off);   off += (size_t)NF * DD / 4;
    unsigned char* if8 = (unsigned char*)(ws + off);   off += (size_t)NF * DD / 4;

    float* out = (float*)d_out;

    int n4 = NF * DD / 4;
    conv_kernel<<<(2 * n4 + 255) / 256, 256, 0, stream>>>(
        user_emb, item_emb, (unsigned int*)uf8, (unsigned int*)if8,
        n4, out, out_size);

    int nent = U + V;
    entity_kernel<<<(nent + 3) / 4, 256, 0, stream>>>(
        uf8, if8, w_user, w_item, bias, h1,
        ufeat, ifeat, p_bf, su, q_bf, sv, U, V);

    mid_kernel<<<GA + GB + POSB, 256, 0, stream>>>(
        p_bf, U, PA, q_bf, V, PB, su, sv, h2, pu, pi, P, posPart);

    neg_reduce_kernel<<<NEGB, 256, 0, stream>>>(PA, PB, h2, posPart, out);
}